// Round 11
// baseline (318.669 us; speedup 1.0000x reference)
//
#include <hip/hip_runtime.h>
#include <hip/hip_fp16.h>
#include <math.h>

#define BN_EPS 1e-5f
#define HF 32          // hidden features
#define BS 256         // nodes per bucket (8-bit dloc)
#define KEDGE 4096     // edges per binsort block (512 thr x 8 edges)
#define MAXNB 800      // max buckets (NB=782 for N=200k)
#define SCAP 5504      // sortb LDS record-stage capacity (44KB)
#define WQ14 16383.0f  // 14-bit norm quantization
#define WQ22 4194303.0f // 22-bit raw-weight quantization (binsort staging)

typedef _Float16 half8 __attribute__((ext_vector_type(8)));
typedef float f32x4 __attribute__((ext_vector_type(4)));
typedef float f32x2 __attribute__((ext_vector_type(2)));

// fast transcendentals (trans pipe)
__device__ __forceinline__ float fsig(float x) {
    return __builtin_amdgcn_rcpf(1.0f + __expf(-x));
}
__device__ __forceinline__ float ftanh(float x) {
    return 1.0f - 2.0f * __builtin_amdgcn_rcpf(1.0f + __expf(2.0f * x));
}

// ---------- fp8 e4m3 (OCP) helpers: HW converters with SW fallback ----------

__device__ __forceinline__ float e4m3_to_f32_sw(unsigned v) {
    unsigned s = v & 0x80u, E = (v >> 3) & 0xFu, m = v & 7u;
    float r = E ? ldexpf((float)(8 + m), (int)E - 10) : ldexpf((float)m, -9);
    return s ? -r : r;
}

__device__ __forceinline__ unsigned f32_to_e4m3_sw(float x) {
    float ax = fabsf(x);
    unsigned s = x < 0.0f ? 0x80u : 0u;
    if (!(ax > 0.0f)) return s;
    if (ax >= 448.0f) return s | 0x7Eu;
    int e;
    float m = frexpf(ax, &e);      // ax = m * 2^e, m in [0.5,1)
    int E = e - 1 + 7;
    if (E >= 1) {
        int q = (int)(m * 16.0f + 0.5f);
        if (q == 16) { q = 8; E += 1; if (E > 15) return s | 0x7Eu; }
        return s | (unsigned)(E << 3) | (unsigned)(q - 8);
    }
    int q = (int)(ax * 512.0f + 0.5f);
    if (q > 7) return s | 0x08u;
    return s | (unsigned)q;
}

__device__ __forceinline__ void dec8(uint2 r, float* f) {
#if __has_builtin(__builtin_amdgcn_cvt_pk_f32_fp8)
    f32x2 p0 = __builtin_amdgcn_cvt_pk_f32_fp8((int)r.x, false);
    f32x2 p1 = __builtin_amdgcn_cvt_pk_f32_fp8((int)r.x, true);
    f32x2 p2 = __builtin_amdgcn_cvt_pk_f32_fp8((int)r.y, false);
    f32x2 p3 = __builtin_amdgcn_cvt_pk_f32_fp8((int)r.y, true);
    f[0] = p0[0]; f[1] = p0[1]; f[2] = p1[0]; f[3] = p1[1];
    f[4] = p2[0]; f[5] = p2[1]; f[6] = p3[0]; f[7] = p3[1];
#else
#pragma unroll
    for (int k = 0; k < 4; ++k) f[k] = e4m3_to_f32_sw((r.x >> (8 * k)) & 0xFFu);
#pragma unroll
    for (int k = 0; k < 4; ++k) f[4 + k] = e4m3_to_f32_sw((r.y >> (8 * k)) & 0xFFu);
#endif
}

__device__ __forceinline__ uint2 enc8(const float* o) {
#if __has_builtin(__builtin_amdgcn_cvt_pk_fp8_f32)
    int w0 = 0, w1 = 0;
    w0 = __builtin_amdgcn_cvt_pk_fp8_f32(o[0], o[1], w0, false);
    w0 = __builtin_amdgcn_cvt_pk_fp8_f32(o[2], o[3], w0, true);
    w1 = __builtin_amdgcn_cvt_pk_fp8_f32(o[4], o[5], w1, false);
    w1 = __builtin_amdgcn_cvt_pk_fp8_f32(o[6], o[7], w1, true);
    return make_uint2((unsigned)w0, (unsigned)w1);
#else
    unsigned a = 0, b = 0;
#pragma unroll
    for (int k = 0; k < 4; ++k) a |= f32_to_e4m3_sw(o[k]) << (8 * k);
#pragma unroll
    for (int k = 0; k < 4; ++k) b |= f32_to_e4m3_sw(o[4 + k]) << (8 * k);
    return make_uint2(a, b);
#endif
}

// ====== 2-stage pipelined gather: rows for batch i issued one batch ahead ======
// (T14 issue-early/consume-late, in registers). For the dominant deg<=16 node all
// 16 row loads are in flight at once. Named A/B buffers -- no runtime-indexed
// arrays (rule: they spill to scratch).
__device__ __forceinline__ void gather_pipe(
        const unsigned* __restrict__ r, int cn,
        const unsigned char* __restrict__ rows, int lane, float* acc) {
    const float qs = 1.0f / WQ14;
    int e = 0;
    uint2 rwA[8], rwB[8];
    float nmA[8], nmB[8];
    if (cn >= 8) {
        uint4 A0 = *(const uint4*)(r), A1 = *(const uint4*)(r + 4);
        unsigned u[8] = {A0.x, A0.y, A0.z, A0.w, A1.x, A1.y, A1.z, A1.w};
#pragma unroll
        for (int q = 0; q < 8; ++q)
            rwA[q] = ((const uint2*)(rows + ((size_t)(u[q] >> 14) << 5)))[lane];
#pragma unroll
        for (int q = 0; q < 8; ++q) nmA[q] = (float)(u[q] & 16383u) * qs;
    }
    if (cn >= 16) {
        uint4 B0 = *(const uint4*)(r + 8), B1 = *(const uint4*)(r + 12);
        unsigned u[8] = {B0.x, B0.y, B0.z, B0.w, B1.x, B1.y, B1.z, B1.w};
#pragma unroll
        for (int q = 0; q < 8; ++q)
            rwB[q] = ((const uint2*)(rows + ((size_t)(u[q] >> 14) << 5)))[lane];
#pragma unroll
        for (int q = 0; q < 8; ++q) nmB[q] = (float)(u[q] & 16383u) * qs;
    }
    while (e + 16 <= cn) {
        // consume A (batch e)
#pragma unroll
        for (int q = 0; q < 8; ++q) {
            float f[8];
            dec8(rwA[q], f);
#pragma unroll
            for (int k = 0; k < 8; ++k) acc[k] += nmA[q] * f[k];
        }
        // refill A <- batch e+16 (latency hides under consume-B)
        if (e + 24 <= cn) {
            uint4 A0 = *(const uint4*)(r + e + 16), A1 = *(const uint4*)(r + e + 20);
            unsigned u[8] = {A0.x, A0.y, A0.z, A0.w, A1.x, A1.y, A1.z, A1.w};
#pragma unroll
            for (int q = 0; q < 8; ++q)
                rwA[q] = ((const uint2*)(rows + ((size_t)(u[q] >> 14) << 5)))[lane];
#pragma unroll
            for (int q = 0; q < 8; ++q) nmA[q] = (float)(u[q] & 16383u) * qs;
        }
        // consume B (batch e+8)
#pragma unroll
        for (int q = 0; q < 8; ++q) {
            float f[8];
            dec8(rwB[q], f);
#pragma unroll
            for (int k = 0; k < 8; ++k) acc[k] += nmB[q] * f[k];
        }
        e += 16;
        // refill B <- batch e+8 (latency hides under next consume-A)
        if (e + 16 <= cn) {
            uint4 B0 = *(const uint4*)(r + e + 8), B1 = *(const uint4*)(r + e + 12);
            unsigned u[8] = {B0.x, B0.y, B0.z, B0.w, B1.x, B1.y, B1.z, B1.w};
#pragma unroll
            for (int q = 0; q < 8; ++q)
                rwB[q] = ((const uint2*)(rows + ((size_t)(u[q] >> 14) << 5)))[lane];
#pragma unroll
            for (int q = 0; q < 8; ++q) nmB[q] = (float)(u[q] & 16383u) * qs;
        }
    }
    if (e + 8 <= cn) {            // one full batch left in A
#pragma unroll
        for (int q = 0; q < 8; ++q) {
            float f[8];
            dec8(rwA[q], f);
#pragma unroll
            for (int k = 0; k < 8; ++k) acc[k] += nmA[q] * f[k];
        }
        e += 8;
    }
    for (; e < cn; ++e) {         // scalar tail
        unsigned u0 = r[e];
        uint2 r0 = ((const uint2*)(rows + ((size_t)(u0 >> 14) << 5)))[lane];
        float n0 = (float)(u0 & 16383u) * qs;
        float f[8];
        dec8(r0, f);
#pragma unroll
        for (int k = 0; k < 8; ++k) acc[k] += n0 * f[k];
    }
}

// ================= Phase A: register-staged direct scatter into buckets =================
// r7 lesson: per-block cost scales with NB, so fewer/fatter blocks win (512 thr x 4096).
// Vector loads; record handling compile-time-indexed (r6's runtime loop spilled).

__global__ __launch_bounds__(512) void k_binsort(
        const int* __restrict__ src, const int* __restrict__ dst,
        const float* __restrict__ ew, int E, int NB, int bcap,
        int* __restrict__ gcur, uint2* __restrict__ recs) {
    __shared__ int hist[MAXNB], curs[MAXNB];

    int tid = threadIdx.x;
    int base = blockIdx.x * KEDGE;
    int cnt = min(KEDGE, E - base);

    for (int i = tid; i < NB; i += 512) hist[i] = 0;
    __syncthreads();

    uint2 rec[8];
    int eb = base + tid * 8;
    int rem = cnt - tid * 8;           // edges owned by this thread (<=0 .. 8)
    if (rem >= 8) {                    // fast path: whole-block for non-tail blocks
        int4 s0 = *(const int4*)(src + eb);
        int4 s1 = *(const int4*)(src + eb + 4);
        int4 d0 = *(const int4*)(dst + eb);
        int4 d1 = *(const int4*)(dst + eb + 4);
        float4 w0 = *(const float4*)(ew + eb);
        float4 w1 = *(const float4*)(ew + eb + 4);
        int ss[8] = {s0.x, s0.y, s0.z, s0.w, s1.x, s1.y, s1.z, s1.w};
        int dd[8] = {d0.x, d0.y, d0.z, d0.w, d1.x, d1.y, d1.z, d1.w};
        float ww[8] = {w0.x, w0.y, w0.z, w0.w, w1.x, w1.y, w1.z, w1.w};
#pragma unroll
        for (int k = 0; k < 8; ++k) {
            unsigned q = (unsigned)(ww[k] * WQ22 + 0.5f);
            if (q > 4194303u) q = 4194303u;
            int b = dd[k] >> 8;
            rec[k] = make_uint2(((unsigned)ss[k] << 8) | (unsigned)(dd[k] & 255),
                                ((unsigned)b << 22) | q);
        }
    } else {
#pragma unroll
        for (int k = 0; k < 8; ++k) {
            if (k < rem) {
                int s = src[eb + k];
                int d = dst[eb + k];
                float w = ew[eb + k];
                unsigned q = (unsigned)(w * WQ22 + 0.5f);
                if (q > 4194303u) q = 4194303u;
                int b = d >> 8;
                rec[k] = make_uint2(((unsigned)s << 8) | (unsigned)(d & 255),
                                    ((unsigned)b << 22) | q);
            }
        }
    }
#pragma unroll
    for (int k = 0; k < 8; ++k)
        if (k < rem) atomicAdd(&hist[rec[k].y >> 22], 1);
    __syncthreads();

    // bucket base in global recs region; curs counts up from it
    for (int b = tid; b < NB; b += 512) {
        int len = hist[b];
        curs[b] = len ? atomicAdd(&gcur[b], len) : 0;
    }
    __syncthreads();

#pragma unroll
    for (int k = 0; k < 8; ++k) {
        if (k < rem) {
            uint2 u = rec[k];
            int b = u.y >> 22;
            int off = atomicAdd(&curs[b], 1);
            if (off < bcap) recs[(size_t)b * bcap + off] = u;
        }
    }
}

// ====== Phase B: 4B records (16B-aligned segs) + CSR + dinv + PRESCALED y1 ======
// 1024 threads; LDS record staging so the CSR scatter never re-reads 25.6MB of
// global. Block 0 also does the one-time weight pack + bias sums + BN fold
// (bnp: [0:32)=sc1, [32:64)=sh1, [64:96)=sc2, [96:128)=sh2).

__global__ __launch_bounds__(1024) void k_sortb(
        const uint2* __restrict__ recs, const int* __restrict__ gcur,
        int bcap, int bcap4,
        const float* __restrict__ x, const float* __restrict__ W1,
        unsigned* __restrict__ recs4, int* __restrict__ pstart,
        int* __restrict__ pcnt, float* __restrict__ dinv,
        unsigned char* __restrict__ y18,
        const float* __restrict__ wih1, const float* __restrict__ bih1,
        const float* __restrict__ bhh1, const float* __restrict__ wih2,
        const float* __restrict__ bih2, const float* __restrict__ bhh2,
        const float* __restrict__ bn1g, const float* __restrict__ bn1b,
        const float* __restrict__ bn1m, const float* __restrict__ bn1v,
        const float* __restrict__ bn2g, const float* __restrict__ bn2b,
        const float* __restrict__ bn2m, const float* __restrict__ bn2v,
        __half* __restrict__ wp1, __half* __restrict__ wp2,
        float* __restrict__ bsum1, float* __restrict__ bsum2,
        float* __restrict__ bnp, int n) {
    __shared__ uint2 srec[SCAP];
    __shared__ int hist[BS], excl4[BS], curs[BS], wsm[BS];
    __shared__ float sdv[BS];
    __shared__ float sW1[128];

    int b = blockIdx.x, tid = threadIdx.x;
    int cnt = min(gcur[b], bcap);
    const uint2* r = recs + (size_t)b * bcap;
    const float dq = 1.0f / WQ22;

    // one-time prep work (block 0 only; independent of this block's bucket work)
    if (b == 0) {
        const int tg[6] = {0, 16, 64, 80, 96, 112};
        for (int idx = tid; idx < 9600; idx += 1024) {
            if (idx < 6144) {
                int t = idx >> 10, rm = idx & 1023;
                int kc = rm >> 9, rm2 = rm & 511;
                int lane = rm2 >> 3, j = rm2 & 7;
                int g = tg[t] + (lane & 15);
                int k = kc * 32 + (lane >> 4) * 8 + j;
                wp1[idx] = __float2half(wih1[g * 64 + k]);
            } else if (idx < 9216) {
                int i2 = idx - 6144;
                int t = i2 >> 9, rm2 = i2 & 511;
                int lane = rm2 >> 3, j = rm2 & 7;
                int g = tg[t] + (lane & 15);
                int k = (lane >> 4) * 8 + j;
                wp2[i2] = __float2half(wih2[g * 32 + k]);
            } else if (idx < 9344) {
                int i = idx - 9216;
                bsum1[i] = bih1[i] + bhh1[i];
            } else if (idx < 9472) {
                int i = idx - 9344;
                bsum2[i] = bih2[i] + bhh2[i];
            } else {
                int f2 = idx - 9472;        // 0..127
                int f = f2 & 31;
                if (f2 < 32) {
                    bnp[f2] = bn1g[f] * rsqrtf(bn1v[f] + BN_EPS);
                } else if (f2 < 64) {
                    float sc = bn1g[f] * rsqrtf(bn1v[f] + BN_EPS);
                    bnp[f2] = bn1b[f] - bn1m[f] * sc;
                } else if (f2 < 96) {
                    bnp[f2] = bn2g[f] * rsqrtf(bn2v[f] + BN_EPS);
                } else {
                    float sc = bn2g[f] * rsqrtf(bn2v[f] + BN_EPS);
                    bnp[f2] = bn2b[f] - bn2m[f] * sc;
                }
            }
        }
    }

    if (tid < BS) { hist[tid] = 0; wsm[tid] = 0; }
    if (tid >= 256 && tid < 384) sW1[tid - 256] = W1[tid - 256];
    __syncthreads();

    for (int i = tid; i < cnt; i += 1024) {
        uint2 u = r[i];
        if (i < SCAP) srec[i] = u;
        int dl = u.x & 255;
        atomicAdd(&hist[dl], 1);
        atomicAdd(&wsm[dl], (int)(u.y & 4194303u));
    }
    __syncthreads();

    if (tid < BS) {
        int g = b * BS + tid;
        sdv[tid] = (g < n) ? rsqrtf(1.0f + (float)wsm[tid] * dq) : 0.0f;
    }
    // exclusive scan over 4-padded lengths -> 16B-aligned per-node segments
    if (tid < 64) {
        int run = 0;
        for (int c = 0; c < BS; c += 64) {
            int idx = c + tid;
            int v = (hist[idx] + 3) & ~3;
            int incl = v;
#pragma unroll
            for (int o = 1; o < 64; o <<= 1) {
                int up = __shfl_up(incl, o, 64);
                if (tid >= o) incl += up;
            }
            int e = run + incl - v;
            excl4[idx] = e; curs[idx] = e;
            run += __shfl(incl, 63, 64);
        }
    }
    __syncthreads();

    unsigned* out4 = recs4 + (size_t)b * bcap4;
    for (int i = tid; i < cnt; i += 1024) {
        uint2 u = (i < SCAP) ? srec[i] : r[i];
        int dl = u.x & 255;
        int pos = atomicAdd(&curs[dl], 1);
        float qn = (float)(u.y & 4194303u) * dq * sdv[dl];  // w * dinv_d
        unsigned q = (unsigned)(qn * WQ14 + 0.5f);
        if (q > 16383u) q = 16383u;
        out4[pos] = ((u.x >> 8) << 14) | q;
    }

    // y18[g] = Q(dinv_g * (x_g @ W1)): 4 threads/node, 8 features each
    {
        int node = tid >> 2, q = tid & 3;
        int g = b * BS + node;
        if (g < n) {
            float4 xv = *(const float4*)(x + (size_t)g * 4);
            float sc = sdv[node];
            int f0 = q * 8;
            float o[8];
#pragma unroll
            for (int k = 0; k < 8; ++k)
                o[k] = sc * (xv.x * sW1[f0 + k] + xv.y * sW1[32 + f0 + k] +
                             xv.z * sW1[64 + f0 + k] + xv.w * sW1[96 + f0 + k]);
            ((uint2*)(y18 + ((size_t)g << 5)))[q] = enc8(o);
        }
    }

    if (tid < BS) {
        int g = b * BS + tid;
        if (g < n) {
            pstart[g] = b * bcap4 + excl4[tid];
            pcnt[g] = hist[tid];
            dinv[g] = sdv[tid];
        }
    }
}

// ====== layer 1: pipelined fp8-row gather + BN + fused xw2 -> A8, skiph(h1) ======

__global__ __launch_bounds__(256) void k_g1w2(
        const unsigned* __restrict__ recs4, const int* __restrict__ pstart,
        const int* __restrict__ pcnt, const float* __restrict__ dinv,
        const unsigned char* __restrict__ y18, const float* __restrict__ W2,
        const float* __restrict__ bias, const float* __restrict__ bnsc,
        const float* __restrict__ bnsh,
        __half* __restrict__ skiph, unsigned char* __restrict__ A8, int n) {
    __shared__ float sW2[1024];
    __shared__ float sh1[64][33];
    int tid = threadIdx.x;

    int nl = tid >> 2;
    int g = blockIdx.x * 64 + nl;
    int lane = tid & 3;
    int fq = lane * 8;
    bool act = g < n;

    // hoisted per-node scalars + self row (latency overlap with sW2 staging)
    float dig = 0.0f;
    int cn = 0;
    const unsigned* r = recs4;
    uint2 sr = make_uint2(0u, 0u);
    if (act) {
        dig = dinv[g];
        cn = pcnt[g];
        r = recs4 + pstart[g];
        sr = ((const uint2*)(y18 + ((size_t)g << 5)))[lane];
    }

    // stage W2 (read only in phase 2 -- no barrier needed here)
    for (int i = tid; i < 1024; i += 256) sW2[i] = W2[i];

    float acc[8];
#pragma unroll
    for (int k = 0; k < 8; ++k) acc[k] = 0.0f;

    if (act) {
        {
            // self-loop: dinv_g * y18hat[g] = dinv_g^2 * y1[g]
            float f[8];
            dec8(sr, f);
#pragma unroll
            for (int k = 0; k < 8; ++k) acc[k] = dig * f[k];
        }
        gather_pipe(r, cn, y18, lane, acc);
    }

    // h1 epilogue: bias + relu + folded BN; stage for xw2; emit fp16 h1 slice
    float o[8];
#pragma unroll
    for (int k = 0; k < 8; ++k) {
        float v = fmaxf(acc[k] + bias[fq + k], 0.0f);
        o[k] = v * bnsc[fq + k] + bnsh[fq + k];
        sh1[nl][fq + k] = o[k];
    }
    if (act) {
        union { __half h[8]; uint4 q; } hv;
#pragma unroll
        for (int k = 0; k < 8; ++k) hv.h[k] = __float2half(o[k]);
        *(uint4*)(skiph + (size_t)g * 32 + fq) = hv.q;
    }
    __syncthreads();

    // phase 2: A8[g] = Q(dinv_g * (h1[g] @ W2)) -> layer-2 rows carry dinv_src
    if (act) {
        float a2[8];
#pragma unroll
        for (int j = 0; j < 8; ++j) a2[j] = 0.0f;
#pragma unroll 4
        for (int k = 0; k < 32; ++k) {
            float h = sh1[nl][k];
            const float* wr = sW2 + k * 32 + fq;
#pragma unroll
            for (int j = 0; j < 8; ++j) a2[j] += h * wr[j];
        }
#pragma unroll
        for (int j = 0; j < 8; ++j) a2[j] *= dig;
        ((uint2*)(A8 + ((size_t)g << 5)))[lane] = enc8(a2);
    }
}

// ===== layer 2 pipelined gather + MFMA head fused: h2 never round-trips HBM =====

__global__ __launch_bounds__(256) void k_g2head(
        const unsigned* __restrict__ recs4, const int* __restrict__ pstart,
        const int* __restrict__ pcnt, const float* __restrict__ dinv,
        const unsigned char* __restrict__ A8,
        const float* __restrict__ bias, const float* __restrict__ bnsc,
        const float* __restrict__ bnsh,
        const __half* __restrict__ skiph, const float* __restrict__ x,
        const __half* __restrict__ wp1, const __half* __restrict__ wp2,
        const float* __restrict__ bsum1, const float* __restrict__ bsum2,
        const float* __restrict__ lw, const float* __restrict__ lb,
        float* __restrict__ out, int n) {
    __shared__ __align__(16) __half h2s[64][40];
    __shared__ __align__(16) __half H1lds[4 * 16 * 40];
    int tid = threadIdx.x;
    int nl = tid >> 2;
    int g = blockIdx.x * 64 + nl;
    int lane = tid & 3;
    int fq = lane * 8;
    bool act = g < n;

    // head-phase coordinates + early h1 prefetch (used only after the gather)
    int w = tid >> 6, l = tid & 63;
    int quad = l >> 4, c = l & 15;
    int node_base = blockIdx.x * 64 + w * 16;
    int arow = node_base + c; if (arow > n - 1) arow = n - 1;
    int lr = arow - blockIdx.x * 64;
    half8 a0 = *(const half8*)(skiph + (size_t)arow * 32 + quad * 8);  // h1

    // hoisted per-node scalars + self row
    float dig = 0.0f;
    int cn = 0;
    const unsigned* r = recs4;
    uint2 sr = make_uint2(0u, 0u);
    if (act) {
        dig = dinv[g];
        cn = pcnt[g];
        r = recs4 + pstart[g];
        sr = ((const uint2*)(A8 + ((size_t)g << 5)))[lane];
    }

    // ---------------- gather phase (h2 = GCN2 output) ----------------
    float acc[8];
#pragma unroll
    for (int k = 0; k < 8; ++k) acc[k] = 0.0f;

    if (act) {
        {
            // self-loop: dinv_g * A8hat[g] = dinv_g^2 * A[g]
            float f[8];
            dec8(sr, f);
#pragma unroll
            for (int k = 0; k < 8; ++k) acc[k] = dig * f[k];
        }
        gather_pipe(r, cn, A8, lane, acc);

        // epilogue: bias + relu + folded BN -> h2 into LDS
        union { __half h[8]; uint4 q; } hv;
#pragma unroll
        for (int k = 0; k < 8; ++k) {
            float v = fmaxf(acc[k] + bias[fq + k], 0.0f);
            hv.h[k] = __float2half(v * bnsc[fq + k] + bnsh[fq + k]);
        }
        *(uint4*)(&h2s[nl][fq]) = hv.q;
    }
    __syncthreads();

    // ---------------- head phase (LSTM1 + LSTM2 + linear) ----------------
    half8 a1 = *(const half8*)(&h2s[lr][quad * 8]);                    // h2 (LDS)

    const half8* b1 = (const half8*)wp1;
    f32x4 d[6];
#pragma unroll
    for (int t = 0; t < 6; ++t) {
        f32x4 ac = {0.0f, 0.0f, 0.0f, 0.0f};
        ac = __builtin_amdgcn_mfma_f32_16x16x32_f16(a0, b1[(t * 2 + 0) * 64 + l], ac, 0, 0, 0);
        ac = __builtin_amdgcn_mfma_f32_16x16x32_f16(a1, b1[(t * 2 + 1) * 64 + l], ac, 0, 0, 0);
        d[t] = ac;
    }

    float bi0 = bsum1[c],      bi1 = bsum1[16 + c];
    float bg0 = bsum1[64 + c], bg1 = bsum1[80 + c];
    float bo0 = bsum1[96 + c], bo1 = bsum1[112 + c];
    float lwc0 = lw[c], lwc1 = lw[c + 16];

    float pa[4];
#pragma unroll
    for (int r2 = 0; r2 < 4; ++r2) {
        float cc0 = fsig(d[0][r2] + bi0) * ftanh(d[2][r2] + bg0);
        float h0 = fsig(d[4][r2] + bo0) * ftanh(cc0);
        float cc1 = fsig(d[1][r2] + bi1) * ftanh(d[3][r2] + bg1);
        float h1 = fsig(d[5][r2] + bo1) * ftanh(cc1);
        pa[r2] = fmaxf(h0, 0.0f) * lwc0 + fmaxf(h1, 0.0f) * lwc1;
        __half* hp = H1lds + (w * 16 + quad * 4 + r2) * 40;
        hp[c] = __float2half(h0);
        hp[c + 16] = __float2half(h1);
    }
    __syncthreads();

    half8 a2 = *(const half8*)(H1lds + (w * 16 + c) * 40 + quad * 8);

    const half8* b2 = (const half8*)wp2;
    f32x4 e2[6];
#pragma unroll
    for (int t = 0; t < 6; ++t) {
        f32x4 ac = {0.0f, 0.0f, 0.0f, 0.0f};
        e2[t] = __builtin_amdgcn_mfma_f32_16x16x32_f16(a2, b2[t * 64 + l], ac, 0, 0, 0);
    }

    float ci0 = bsum2[c],      ci1 = bsum2[16 + c];
    float cg0 = bsum2[64 + c], cg1 = bsum2[80 + c];
    float co0 = bsum2[96 + c], co1 = bsum2[112 + c];
    float lw2c0 = lw[32 + c], lw2c1 = lw[48 + c];
#pragma unroll
    for (int r2 = 0; r2 < 4; ++r2) {
        float cc0 = fsig(e2[0][r2] + ci0) * ftanh(e2[2][r2] + cg0);
        float h0 = fsig(e2[4][r2] + co0) * ftanh(cc0);
        float cc1 = fsig(e2[1][r2] + ci1) * ftanh(e2[3][r2] + cg1);
        float h1 = fsig(e2[5][r2] + co1) * ftanh(cc1);
        pa[r2] += fmaxf(h0, 0.0f) * lw2c0 + fmaxf(h1, 0.0f) * lw2c1;
    }

#pragma unroll
    for (int m = 1; m < 16; m <<= 1) {
#pragma unroll
        for (int r2 = 0; r2 < 4; ++r2) pa[r2] += __shfl_xor(pa[r2], m, 64);
    }

    if (c < 4) {
        int node = node_base + quad * 4 + c;
        if (node < n) {
            const float4 xv = *(const float4*)(x + (size_t)node * 4);
            out[node] = pa[c] + lb[0]
                + fmaxf(xv.x, 0.0f) * lw[64] + fmaxf(xv.y, 0.0f) * lw[65]
                + fmaxf(xv.z, 0.0f) * lw[66] + fmaxf(xv.w, 0.0f) * lw[67];
        }
    }
}

// ================= fallback (atomic scatter, fp32) =================

__global__ void k_initdeg(float* __restrict__ deg, int n) {
    int i = blockIdx.x * blockDim.x + threadIdx.x;
    if (i < n) deg[i] = 1.0f;
}

__global__ void k_deg_only(const int* __restrict__ dst, const float* __restrict__ ew,
                           float* __restrict__ deg, int E) {
    int e = blockIdx.x * blockDim.x + threadIdx.x;
    if (e < E) atomicAdd(&deg[dst[e]], ew[e]);
}

__global__ void k_dinv_f(float* __restrict__ deg, int n) {
    int i = blockIdx.x * blockDim.x + threadIdx.x;
    if (i < n) {
        float d = deg[i];
        deg[i] = d > 0.0f ? rsqrtf(d) : 0.0f;
    }
}

__global__ void k_xw1_f(const float* __restrict__ x, const float* __restrict__ W,
                        float* __restrict__ out, int n) {
    int idx = blockIdx.x * blockDim.x + threadIdx.x;
    if (idx >= n * HF) return;
    int nn = idx >> 5, f = idx & 31;
    const float4 xr = *(const float4*)(x + (size_t)nn * 4);
    out[idx] = xr.x * W[f] + xr.y * W[32 + f] + xr.z * W[64 + f] + xr.w * W[96 + f];
}

__global__ void k_xw2_f(const float* __restrict__ Hin, const float* __restrict__ W,
                        float* __restrict__ out, int n) {
    __shared__ float sW[32 * 32];
    __shared__ float sH[8][32];
    int tid = threadIdx.x;
    for (int i = tid; i < 1024; i += 256) sW[i] = W[i];
    int r = tid >> 5, f = tid & 31;
    int nn = blockIdx.x * 8 + r;
    if (nn < n) sH[r][f] = Hin[(size_t)nn * HF + f];
    __syncthreads();
    if (nn >= n) return;
    float acc = 0.0f;
#pragma unroll
    for (int k = 0; k < 32; ++k) acc += sH[r][k] * sW[k * 32 + f];
    out[(size_t)nn * HF + f] = acc;
}

__global__ void k_selfloop(const float* __restrict__ A, const float* __restrict__ dinv,
                           float* __restrict__ B, int n) {
    int idx = blockIdx.x * blockDim.x + threadIdx.x;
    if (idx >= n * HF) return;
    int nn = idx >> 5;
    float di = dinv[nn];
    B[idx] = di * di * A[idx];
}

__global__ void k_scatter(const int* __restrict__ src, const int* __restrict__ dst,
                          const float* __restrict__ ew, const float* __restrict__ dinv,
                          const float* __restrict__ A, float* __restrict__ B, int total) {
    int idx = blockIdx.x * blockDim.x + threadIdx.x;
    if (idx >= total) return;
    int e = idx >> 5, f = idx & 31;
    int s = src[e], d = dst[e];
    float norm = dinv[s] * ew[e] * dinv[d];
    atomicAdd(&B[d * HF + f], norm * A[s * HF + f]);
}

__global__ void k_post(const float* __restrict__ B, const float* __restrict__ bias,
                       const float* __restrict__ gamma, const float* __restrict__ beta,
                       const float* __restrict__ mean, const float* __restrict__ var,
                       float* __restrict__ Hout, int n) {
    int idx = blockIdx.x * blockDim.x + threadIdx.x;
    if (idx >= n * HF) return;
    int f = idx & 31;
    float v = fmaxf(B[idx] + bias[f], 0.0f);
    float sc = gamma[f] * rsqrtf(var[f] + BN_EPS);
    Hout[idx] = (v - mean[f]) * sc + beta[f];
}

__global__ __launch_bounds__(256) void k_head(
        const float* __restrict__ h1, const float* __restrict__ h2,
        const float* __restrict__ x,
        const float* __restrict__ wih1, const float* __restrict__ bih1, const float* __restrict__ bhh1,
        const float* __restrict__ wih2, const float* __restrict__ bih2, const float* __restrict__ bhh2,
        const float* __restrict__ lw, const float* __restrict__ lb,
        float* __restrict__ out, int n) {
    __shared__ float sH1[32 * 256];
    int tid = threadIdx.x;
    int nn = blockIdx.x * 256 + tid;
    if (nn >= n) return;

    const float4* a = (const float4*)(h1 + (size_t)nn * HF);
    const float4* b = (const float4*)(h2 + (size_t)nn * HF);
    float skip[64];
#pragma unroll
    for (int q = 0; q < 8; ++q) {
        float4 v = a[q];
        skip[4 * q] = v.x; skip[4 * q + 1] = v.y; skip[4 * q + 2] = v.z; skip[4 * q + 3] = v.w;
        float4 u = b[q];
        skip[32 + 4 * q] = u.x; skip[33 + 4 * q] = u.y; skip[34 + 4 * q] = u.z; skip[35 + 4 * q] = u.w;
    }

    float oa = lb[0];
#pragma unroll 1
    for (int j = 0; j < 32; ++j) {
        const float4* wi = (const float4*)(wih1 + (size_t)j * 64);
        const float4* wg = (const float4*)(wih1 + (size_t)(64 + j) * 64);
        const float4* wo = (const float4*)(wih1 + (size_t)(96 + j) * 64);
        float gi = bih1[j] + bhh1[j];
        float gg = bih1[64 + j] + bhh1[64 + j];
        float go = bih1[96 + j] + bhh1[96 + j];
#pragma unroll
        for (int q = 0; q < 16; ++q) {
            float4 aa = wi[q], bb = wg[q], cc4 = wo[q];
            float s0 = skip[4 * q], s1 = skip[4 * q + 1], s2 = skip[4 * q + 2], s3 = skip[4 * q + 3];
            gi += aa.x * s0 + aa.y * s1 + aa.z * s2 + aa.w * s3;
            gg += bb.x * s0 + bb.y * s1 + bb.z * s2 + bb.w * s3;
            go += cc4.x * s0 + cc4.y * s1 + cc4.z * s2 + cc4.w * s3;
        }
        float cc = fsig(gi) * ftanh(gg);
        float hh = fsig(go) * ftanh(cc);
        sH1[j * 256 + tid] = hh;
        oa += fmaxf(hh, 0.0f) * lw[j];
    }

#pragma unroll 1
    for (int j = 0; j < 32; ++j) {
        const float4* wi = (const float4*)(wih2 + (size_t)j * 32);
        const float4* wg = (const float4*)(wih2 + (size_t)(64 + j) * 32);
        const float4* wo = (const float4*)(wih2 + (size_t)(96 + j) * 32);
        float gi = bih2[j] + bhh2[j];
        float gg = bih2[64 + j] + bhh2[64 + j];
        float go = bih2[96 + j] + bhh2[96 + j];
#pragma unroll
        for (int q = 0; q < 8; ++q) {
            float4 aa = wi[q], bb = wg[q], cc4 = wo[q];
            float s0 = sH1[(4 * q) * 256 + tid], s1 = sH1[(4 * q + 1) * 256 + tid];
            float s2 = sH1[(4 * q + 2) * 256 + tid], s3 = sH1[(4 * q + 3) * 256 + tid];
            gi += aa.x * s0 + aa.y * s1 + aa.z * s2 + aa.w * s3;
            gg += bb.x * s0 + bb.y * s1 + bb.z * s2 + bb.w * s3;
            go += cc4.x * s0 + cc4.y * s1 + cc4.z * s2 + cc4.w * s3;
        }
        float cc = fsig(gi) * ftanh(gg);
        float hh = fsig(go) * ftanh(cc);
        oa += fmaxf(hh, 0.0f) * lw[32 + j];
    }

    const float4 xv = *(const float4*)(x + (size_t)nn * 4);
    oa += fmaxf(xv.x, 0.0f) * lw[64] + fmaxf(xv.y, 0.0f) * lw[65] +
          fmaxf(xv.z, 0.0f) * lw[66] + fmaxf(xv.w, 0.0f) * lw[67];
    out[nn] = oa;
}

// ================= launch =================

extern "C" void kernel_launch(void* const* d_in, const int* in_sizes, int n_in,
                              void* d_out, int out_size, void* d_ws, size_t ws_size,
                              hipStream_t stream) {
    const float* x   = (const float*)d_in[0];
    const int*   ei  = (const int*)d_in[1];
    const float* ew  = (const float*)d_in[2];
    const float* g1w = (const float*)d_in[3];
    const float* g1b = (const float*)d_in[4];
    const float* g2w = (const float*)d_in[5];
    const float* g2b = (const float*)d_in[6];
    const float* bn1g = (const float*)d_in[7];
    const float* bn1b = (const float*)d_in[8];
    const float* bn1m = (const float*)d_in[9];
    const float* bn1v = (const float*)d_in[10];
    const float* bn2g = (const float*)d_in[11];
    const float* bn2b = (const float*)d_in[12];
    const float* bn2m = (const float*)d_in[13];
    const float* bn2v = (const float*)d_in[14];
    const float* w1ih = (const float*)d_in[15];
    const float* b1ih = (const float*)d_in[17];
    const float* b1hh = (const float*)d_in[18];
    const float* w2ih = (const float*)d_in[19];
    const float* b2ih = (const float*)d_in[21];
    const float* b2hh = (const float*)d_in[22];
    const float* lw   = (const float*)d_in[23];
    const float* lb   = (const float*)d_in[24];
    float* out = (float*)d_out;

    const int N = in_sizes[0] / 4;
    const int E = in_sizes[2];
    const int* src = ei;
    const int* dst = ei + E;

    const int T = 256;
    const int NB = (N + BS - 1) / BS;
    long long meanb = ((long long)BS * E) / (N > 0 ? N : 1);
    int bcap = (int)(meanb + meanb / 4 + 128);
    bcap = (bcap + 3) & ~3;
    int bcap4 = bcap + 3 * BS;  // room for per-node 16B-alignment padding

    // workspace layout (256B-aligned regions)
    char* p = (char*)d_ws;
    auto alloc = [&](size_t bytes) { char* q = p; p += (bytes + 255) & ~(size_t)255; return q; };
    int*      gcur   = (int*)alloc(sizeof(int) * NB);
    uint2*    recs   = (uint2*)alloc(sizeof(uint2) * (size_t)NB * bcap);
    unsigned* recs4  = (unsigned*)alloc(sizeof(unsigned) * (size_t)NB * bcap4);
    float*    dinv   = (float*)alloc(sizeof(float) * N);
    int*      pstart = (int*)alloc(sizeof(int) * N);
    int*      pcnt   = (int*)alloc(sizeof(int) * N);
    unsigned char* y18 = (unsigned char*)alloc((size_t)N * HF);         // fp8 dinv*(x@W1)
    unsigned char* A8  = (unsigned char*)alloc((size_t)N * HF);         // fp8 dinv*(h1@W2)
    __half*   skiph  = (__half*)alloc(sizeof(__half) * (size_t)N * 32); // h1 f16 only
    __half*   wp1    = (__half*)alloc(sizeof(__half) * 6144);
    __half*   wp2    = (__half*)alloc(sizeof(__half) * 3072);
    float*    bsum1  = (float*)alloc(sizeof(float) * 128);
    float*    bsum2  = (float*)alloc(sizeof(float) * 128);
    float*    bnp    = (float*)alloc(sizeof(float) * 128);  // folded BN sc/sh
    size_t need = (size_t)(p - (char*)d_ws);

    int bN  = (N + T - 1) / T;
    int bE  = (E + T - 1) / T;
    int bNF = (N * HF + T - 1) / T;
    int bN8 = (N + 7) / 8;
    int bG  = (N + 63) / 64;
    int bBin = (E + KEDGE - 1) / KEDGE;

    if (ws_size >= need && NB <= MAXNB && N <= (1 << 18) && bcap <= SCAP) {
        // ---- build: memset cursor + bucket scatter + CSR/prep ----
        hipMemsetAsync(gcur, 0, sizeof(int) * NB, stream);
        k_binsort<<<bBin, 512, 0, stream>>>(src, dst, ew, E, NB, bcap, gcur, recs);
        k_sortb<<<NB, 1024, 0, stream>>>(recs, gcur, bcap, bcap4, x, g1w,
                                         recs4, pstart, pcnt, dinv, y18,
                                         w1ih, b1ih, b1hh, w2ih, b2ih, b2hh,
                                         bn1g, bn1b, bn1m, bn1v,
                                         bn2g, bn2b, bn2m, bn2v,
                                         wp1, wp2, bsum1, bsum2, bnp, N);

        // ---- layer 1: pipelined gather over prescaled y1 + fused xw2 ----
        k_g1w2<<<bG, T, 0, stream>>>(recs4, pstart, pcnt, dinv, y18, g2w,
                                     g1b, bnp, bnp + 32, skiph, A8, N);
        // ---- layer 2 pipelined gather + MFMA head fused ----
        k_g2head<<<bG, T, 0, stream>>>(recs4, pstart, pcnt, dinv, A8,
                                       g2b, bnp + 64, bnp + 96,
                                       skiph, x, wp1, wp2, bsum1, bsum2,
                                       lw, lb, out, N);
    } else {
        // ---- fallback: atomic scatter, fp32 ----
        size_t Npad = ((size_t)N + 255) & ~(size_t)255;
        float* fdinv = (float*)d_ws;
        float* fA = fdinv + Npad;
        float* fB = fA + (size_t)N * HF;
        float* fC = fB + (size_t)N * HF;
        int bEF = (int)(((long long)E * HF + T - 1) / T);
        int bH = (N + 255) / 256;

        k_initdeg<<<bN, T, 0, stream>>>(fdinv, N);
        k_deg_only<<<bE, T, 0, stream>>>(dst, ew, fdinv, E);
        k_dinv_f<<<bN, T, 0, stream>>>(fdinv, N);

        k_xw1_f<<<bNF, T, 0, stream>>>(x, g1w, fA, N);
        k_selfloop<<<bNF, T, 0, stream>>>(fA, fdinv, fB, N);
        k_scatter<<<bEF, T, 0, stream>>>(src, dst, ew, fdinv, fA, fB, E * HF);
        k_post<<<bNF, T, 0, stream>>>(fB, g1b, bn1g, bn1b, bn1m, bn1v, fC, N);

        k_xw2_f<<<bN8, T, 0, stream>>>(fC, g2w, fA, N);
        k_selfloop<<<bNF, T, 0, stream>>>(fA, fdinv, fB, N);
        k_scatter<<<bEF, T, 0, stream>>>(src, dst, ew, fdinv, fA, fB, E * HF);
        k_post<<<bNF, T, 0, stream>>>(fB, g2b, bn2g, bn2b, bn2m, bn2v, fB, N);

        k_head<<<bH, T, 0, stream>>>(fC, fB, x, w1ih, b1ih, b1hh, w2ih, b2ih, b2hh,
                                     lw, lb, out, N);
    }
}

// Round 12
// 293.672 us; speedup vs baseline: 1.0851x; 1.0851x over previous
//
#include <hip/hip_runtime.h>
#include <hip/hip_fp16.h>
#include <math.h>

#define BN_EPS 1e-5f
#define HF 32          // hidden features
#define BS 256         // nodes per bucket (8-bit dloc)
#define KEDGE 4096     // edges per binsort block (512 thr x 8 edges)
#define MAXNB 800      // max buckets (NB=782 for N=200k)
#define SCAP 5504      // sortb LDS record-stage capacity (44KB)
#define WQ14 16383.0f  // 14-bit norm quantization
#define WQ22 4194303.0f // 22-bit raw-weight quantization (binsort staging)

typedef _Float16 half8 __attribute__((ext_vector_type(8)));
typedef float f32x4 __attribute__((ext_vector_type(4)));
typedef float f32x2 __attribute__((ext_vector_type(2)));

// fast transcendentals (trans pipe)
__device__ __forceinline__ float fsig(float x) {
    return __builtin_amdgcn_rcpf(1.0f + __expf(-x));
}
__device__ __forceinline__ float ftanh(float x) {
    return 1.0f - 2.0f * __builtin_amdgcn_rcpf(1.0f + __expf(2.0f * x));
}

// ---------- fp8 e4m3 (OCP) helpers: HW converters with SW fallback ----------

__device__ __forceinline__ float e4m3_to_f32_sw(unsigned v) {
    unsigned s = v & 0x80u, E = (v >> 3) & 0xFu, m = v & 7u;
    float r = E ? ldexpf((float)(8 + m), (int)E - 10) : ldexpf((float)m, -9);
    return s ? -r : r;
}

__device__ __forceinline__ unsigned f32_to_e4m3_sw(float x) {
    float ax = fabsf(x);
    unsigned s = x < 0.0f ? 0x80u : 0u;
    if (!(ax > 0.0f)) return s;
    if (ax >= 448.0f) return s | 0x7Eu;
    int e;
    float m = frexpf(ax, &e);      // ax = m * 2^e, m in [0.5,1)
    int E = e - 1 + 7;
    if (E >= 1) {
        int q = (int)(m * 16.0f + 0.5f);
        if (q == 16) { q = 8; E += 1; if (E > 15) return s | 0x7Eu; }
        return s | (unsigned)(E << 3) | (unsigned)(q - 8);
    }
    int q = (int)(ax * 512.0f + 0.5f);
    if (q > 7) return s | 0x08u;
    return s | (unsigned)q;
}

__device__ __forceinline__ void dec8(uint2 r, float* f) {
#if __has_builtin(__builtin_amdgcn_cvt_pk_f32_fp8)
    f32x2 p0 = __builtin_amdgcn_cvt_pk_f32_fp8((int)r.x, false);
    f32x2 p1 = __builtin_amdgcn_cvt_pk_f32_fp8((int)r.x, true);
    f32x2 p2 = __builtin_amdgcn_cvt_pk_f32_fp8((int)r.y, false);
    f32x2 p3 = __builtin_amdgcn_cvt_pk_f32_fp8((int)r.y, true);
    f[0] = p0[0]; f[1] = p0[1]; f[2] = p1[0]; f[3] = p1[1];
    f[4] = p2[0]; f[5] = p2[1]; f[6] = p3[0]; f[7] = p3[1];
#else
#pragma unroll
    for (int k = 0; k < 4; ++k) f[k] = e4m3_to_f32_sw((r.x >> (8 * k)) & 0xFFu);
#pragma unroll
    for (int k = 0; k < 4; ++k) f[4 + k] = e4m3_to_f32_sw((r.y >> (8 * k)) & 0xFFu);
#endif
}

__device__ __forceinline__ uint2 enc8(const float* o) {
#if __has_builtin(__builtin_amdgcn_cvt_pk_fp8_f32)
    int w0 = 0, w1 = 0;
    w0 = __builtin_amdgcn_cvt_pk_fp8_f32(o[0], o[1], w0, false);
    w0 = __builtin_amdgcn_cvt_pk_fp8_f32(o[2], o[3], w0, true);
    w1 = __builtin_amdgcn_cvt_pk_fp8_f32(o[4], o[5], w1, false);
    w1 = __builtin_amdgcn_cvt_pk_fp8_f32(o[6], o[7], w1, true);
    return make_uint2((unsigned)w0, (unsigned)w1);
#else
    unsigned a = 0, b = 0;
#pragma unroll
    for (int k = 0; k < 4; ++k) a |= f32_to_e4m3_sw(o[k]) << (8 * k);
#pragma unroll
    for (int k = 0; k < 4; ++k) b |= f32_to_e4m3_sw(o[4 + k]) << (8 * k);
    return make_uint2(a, b);
#endif
}

// ================= Phase A: register-staged direct scatter into buckets =================
// r7 lesson: per-block cost scales with NB, so fewer/fatter blocks win (512 thr x 4096).
// Vector loads; record handling compile-time-indexed (r6's runtime loop spilled).

__global__ __launch_bounds__(512) void k_binsort(
        const int* __restrict__ src, const int* __restrict__ dst,
        const float* __restrict__ ew, int E, int NB, int bcap,
        int* __restrict__ gcur, uint2* __restrict__ recs) {
    __shared__ int hist[MAXNB], curs[MAXNB];

    int tid = threadIdx.x;
    int base = blockIdx.x * KEDGE;
    int cnt = min(KEDGE, E - base);

    for (int i = tid; i < NB; i += 512) hist[i] = 0;
    __syncthreads();

    uint2 rec[8];
    int eb = base + tid * 8;
    int rem = cnt - tid * 8;           // edges owned by this thread (<=0 .. 8)
    if (rem >= 8) {                    // fast path: whole-block for non-tail blocks
        int4 s0 = *(const int4*)(src + eb);
        int4 s1 = *(const int4*)(src + eb + 4);
        int4 d0 = *(const int4*)(dst + eb);
        int4 d1 = *(const int4*)(dst + eb + 4);
        float4 w0 = *(const float4*)(ew + eb);
        float4 w1 = *(const float4*)(ew + eb + 4);
        int ss[8] = {s0.x, s0.y, s0.z, s0.w, s1.x, s1.y, s1.z, s1.w};
        int dd[8] = {d0.x, d0.y, d0.z, d0.w, d1.x, d1.y, d1.z, d1.w};
        float ww[8] = {w0.x, w0.y, w0.z, w0.w, w1.x, w1.y, w1.z, w1.w};
#pragma unroll
        for (int k = 0; k < 8; ++k) {
            unsigned q = (unsigned)(ww[k] * WQ22 + 0.5f);
            if (q > 4194303u) q = 4194303u;
            int b = dd[k] >> 8;
            rec[k] = make_uint2(((unsigned)ss[k] << 8) | (unsigned)(dd[k] & 255),
                                ((unsigned)b << 22) | q);
        }
    } else {
#pragma unroll
        for (int k = 0; k < 8; ++k) {
            if (k < rem) {
                int s = src[eb + k];
                int d = dst[eb + k];
                float w = ew[eb + k];
                unsigned q = (unsigned)(w * WQ22 + 0.5f);
                if (q > 4194303u) q = 4194303u;
                int b = d >> 8;
                rec[k] = make_uint2(((unsigned)s << 8) | (unsigned)(d & 255),
                                    ((unsigned)b << 22) | q);
            }
        }
    }
#pragma unroll
    for (int k = 0; k < 8; ++k)
        if (k < rem) atomicAdd(&hist[rec[k].y >> 22], 1);
    __syncthreads();

    // bucket base in global recs region; curs counts up from it
    for (int b = tid; b < NB; b += 512) {
        int len = hist[b];
        curs[b] = len ? atomicAdd(&gcur[b], len) : 0;
    }
    __syncthreads();

#pragma unroll
    for (int k = 0; k < 8; ++k) {
        if (k < rem) {
            uint2 u = rec[k];
            int b = u.y >> 22;
            int off = atomicAdd(&curs[b], 1);
            if (off < bcap) recs[(size_t)b * bcap + off] = u;
        }
    }
}

// ====== Phase B: 4B records (16B-aligned segs) + CSR + dinv + PRESCALED y1 ======
// 1024 threads; LDS record staging so the CSR scatter never re-reads 25.6MB of
// global. Block 0 also does the one-time weight pack + bias sums + BN fold
// (bnp: [0:32)=sc1, [32:64)=sh1, [64:96)=sc2, [96:128)=sh2).

__global__ __launch_bounds__(1024) void k_sortb(
        const uint2* __restrict__ recs, const int* __restrict__ gcur,
        int bcap, int bcap4,
        const float* __restrict__ x, const float* __restrict__ W1,
        unsigned* __restrict__ recs4, int* __restrict__ pstart,
        int* __restrict__ pcnt, float* __restrict__ dinv,
        unsigned char* __restrict__ y18,
        const float* __restrict__ wih1, const float* __restrict__ bih1,
        const float* __restrict__ bhh1, const float* __restrict__ wih2,
        const float* __restrict__ bih2, const float* __restrict__ bhh2,
        const float* __restrict__ bn1g, const float* __restrict__ bn1b,
        const float* __restrict__ bn1m, const float* __restrict__ bn1v,
        const float* __restrict__ bn2g, const float* __restrict__ bn2b,
        const float* __restrict__ bn2m, const float* __restrict__ bn2v,
        __half* __restrict__ wp1, __half* __restrict__ wp2,
        float* __restrict__ bsum1, float* __restrict__ bsum2,
        float* __restrict__ bnp, int n) {
    __shared__ uint2 srec[SCAP];
    __shared__ int hist[BS], excl4[BS], curs[BS], wsm[BS];
    __shared__ float sdv[BS];
    __shared__ float sW1[128];

    int b = blockIdx.x, tid = threadIdx.x;
    int cnt = min(gcur[b], bcap);
    const uint2* r = recs + (size_t)b * bcap;
    const float dq = 1.0f / WQ22;

    // one-time prep work (block 0 only; independent of this block's bucket work)
    if (b == 0) {
        const int tg[6] = {0, 16, 64, 80, 96, 112};
        for (int idx = tid; idx < 9600; idx += 1024) {
            if (idx < 6144) {
                int t = idx >> 10, rm = idx & 1023;
                int kc = rm >> 9, rm2 = rm & 511;
                int lane = rm2 >> 3, j = rm2 & 7;
                int g = tg[t] + (lane & 15);
                int k = kc * 32 + (lane >> 4) * 8 + j;
                wp1[idx] = __float2half(wih1[g * 64 + k]);
            } else if (idx < 9216) {
                int i2 = idx - 6144;
                int t = i2 >> 9, rm2 = i2 & 511;
                int lane = rm2 >> 3, j = rm2 & 7;
                int g = tg[t] + (lane & 15);
                int k = (lane >> 4) * 8 + j;
                wp2[i2] = __float2half(wih2[g * 32 + k]);
            } else if (idx < 9344) {
                int i = idx - 9216;
                bsum1[i] = bih1[i] + bhh1[i];
            } else if (idx < 9472) {
                int i = idx - 9344;
                bsum2[i] = bih2[i] + bhh2[i];
            } else {
                int f2 = idx - 9472;        // 0..127
                int f = f2 & 31;
                if (f2 < 32) {
                    bnp[f2] = bn1g[f] * rsqrtf(bn1v[f] + BN_EPS);
                } else if (f2 < 64) {
                    float sc = bn1g[f] * rsqrtf(bn1v[f] + BN_EPS);
                    bnp[f2] = bn1b[f] - bn1m[f] * sc;
                } else if (f2 < 96) {
                    bnp[f2] = bn2g[f] * rsqrtf(bn2v[f] + BN_EPS);
                } else {
                    float sc = bn2g[f] * rsqrtf(bn2v[f] + BN_EPS);
                    bnp[f2] = bn2b[f] - bn2m[f] * sc;
                }
            }
        }
    }

    if (tid < BS) { hist[tid] = 0; wsm[tid] = 0; }
    if (tid >= 256 && tid < 384) sW1[tid - 256] = W1[tid - 256];
    __syncthreads();

    for (int i = tid; i < cnt; i += 1024) {
        uint2 u = r[i];
        if (i < SCAP) srec[i] = u;
        int dl = u.x & 255;
        atomicAdd(&hist[dl], 1);
        atomicAdd(&wsm[dl], (int)(u.y & 4194303u));
    }
    __syncthreads();

    if (tid < BS) {
        int g = b * BS + tid;
        sdv[tid] = (g < n) ? rsqrtf(1.0f + (float)wsm[tid] * dq) : 0.0f;
    }
    // exclusive scan over 4-padded lengths -> 16B-aligned per-node segments
    if (tid < 64) {
        int run = 0;
        for (int c = 0; c < BS; c += 64) {
            int idx = c + tid;
            int v = (hist[idx] + 3) & ~3;
            int incl = v;
#pragma unroll
            for (int o = 1; o < 64; o <<= 1) {
                int up = __shfl_up(incl, o, 64);
                if (tid >= o) incl += up;
            }
            int e = run + incl - v;
            excl4[idx] = e; curs[idx] = e;
            run += __shfl(incl, 63, 64);
        }
    }
    __syncthreads();

    unsigned* out4 = recs4 + (size_t)b * bcap4;
    for (int i = tid; i < cnt; i += 1024) {
        uint2 u = (i < SCAP) ? srec[i] : r[i];
        int dl = u.x & 255;
        int pos = atomicAdd(&curs[dl], 1);
        float qn = (float)(u.y & 4194303u) * dq * sdv[dl];  // w * dinv_d
        unsigned q = (unsigned)(qn * WQ14 + 0.5f);
        if (q > 16383u) q = 16383u;
        out4[pos] = ((u.x >> 8) << 14) | q;
    }

    // y18[g] = Q(dinv_g * (x_g @ W1)): 4 threads/node, 8 features each
    {
        int node = tid >> 2, q = tid & 3;
        int g = b * BS + node;
        if (g < n) {
            float4 xv = *(const float4*)(x + (size_t)g * 4);
            float sc = sdv[node];
            int f0 = q * 8;
            float o[8];
#pragma unroll
            for (int k = 0; k < 8; ++k)
                o[k] = sc * (xv.x * sW1[f0 + k] + xv.y * sW1[32 + f0 + k] +
                             xv.z * sW1[64 + f0 + k] + xv.w * sW1[96 + f0 + k]);
            ((uint2*)(y18 + ((size_t)g << 5)))[q] = enc8(o);
        }
    }

    if (tid < BS) {
        int g = b * BS + tid;
        if (g < n) {
            pstart[g] = b * bcap4 + excl4[tid];
            pcnt[g] = hist[tid];
            dinv[g] = sdv[tid];
        }
    }
}

// ====== layer 1: fp8-row gather over prescaled y1 + BN + fused xw2 -> A8, skiph(h1) ======
// r10 operating point (confirmed best): depth-1 record prefetch, rows just-in-time,
// ~60 VGPR. r11 showed depth-2 register pipelining trades occupancy (92 VGPR, 20%)
// for ILP at a net loss -- do not deepen.

__global__ __launch_bounds__(256) void k_g1w2(
        const unsigned* __restrict__ recs4, const int* __restrict__ pstart,
        const int* __restrict__ pcnt, const float* __restrict__ dinv,
        const unsigned char* __restrict__ y18, const float* __restrict__ W2,
        const float* __restrict__ bias, const float* __restrict__ bnsc,
        const float* __restrict__ bnsh,
        __half* __restrict__ skiph, unsigned char* __restrict__ A8, int n) {
    __shared__ float sW2[1024];
    __shared__ float sh1[64][33];
    int tid = threadIdx.x;

    int nl = tid >> 2;
    int g = blockIdx.x * 64 + nl;
    int lane = tid & 3;
    int fq = lane * 8;
    bool act = g < n;

    // hoisted per-node scalars + self row (latency overlap with sW2 staging)
    float dig = 0.0f;
    int cn = 0;
    const unsigned* r = recs4;
    uint2 sr = make_uint2(0u, 0u);
    if (act) {
        dig = dinv[g];
        cn = pcnt[g];
        r = recs4 + pstart[g];
        sr = ((const uint2*)(y18 + ((size_t)g << 5)))[lane];
    }

    // stage W2 (read only in phase 2 -- no barrier needed here)
    for (int i = tid; i < 1024; i += 256) sW2[i] = W2[i];

    float acc[8];
#pragma unroll
    for (int k = 0; k < 8; ++k) acc[k] = 0.0f;

    if (act) {
        {
            // self-loop: dinv_g * y18hat[g] = dinv_g^2 * y1[g]
            float f[8];
            dec8(sr, f);
#pragma unroll
            for (int k = 0; k < 8; ++k) acc[k] = dig * f[k];
        }

        const float qs = 1.0f / WQ14;
        uint4 na, nb;
        if (8 <= cn) { na = *(const uint4*)(r); nb = *(const uint4*)(r + 4); }
        int e = 0;
        for (; e + 8 <= cn; e += 8) {
            uint4 ua = na, ub = nb;
            if (e + 16 <= cn) { na = *(const uint4*)(r + e + 8); nb = *(const uint4*)(r + e + 12); }
            unsigned u[8] = {ua.x, ua.y, ua.z, ua.w, ub.x, ub.y, ub.z, ub.w};
            uint2 rw[8];
#pragma unroll
            for (int q = 0; q < 8; ++q)
                rw[q] = ((const uint2*)(y18 + ((size_t)(u[q] >> 14) << 5)))[lane];
            float nm[8];
#pragma unroll
            for (int q = 0; q < 8; ++q)
                nm[q] = (float)(u[q] & 16383u) * qs;
#pragma unroll
            for (int q = 0; q < 8; ++q) {
                float f[8];
                dec8(rw[q], f);
#pragma unroll
                for (int k = 0; k < 8; ++k) acc[k] += nm[q] * f[k];
            }
        }
        for (; e < cn; ++e) {
            unsigned u0 = r[e];
            uint2 r0 = ((const uint2*)(y18 + ((size_t)(u0 >> 14) << 5)))[lane];
            float n0 = (float)(u0 & 16383u) * qs;
            float f[8];
            dec8(r0, f);
#pragma unroll
            for (int k = 0; k < 8; ++k) acc[k] += n0 * f[k];
        }
    }

    // h1 epilogue: bias + relu + folded BN; stage for xw2; emit fp16 h1 slice
    float o[8];
#pragma unroll
    for (int k = 0; k < 8; ++k) {
        float v = fmaxf(acc[k] + bias[fq + k], 0.0f);
        o[k] = v * bnsc[fq + k] + bnsh[fq + k];
        sh1[nl][fq + k] = o[k];
    }
    if (act) {
        union { __half h[8]; uint4 q; } hv;
#pragma unroll
        for (int k = 0; k < 8; ++k) hv.h[k] = __float2half(o[k]);
        *(uint4*)(skiph + (size_t)g * 32 + fq) = hv.q;
    }
    __syncthreads();

    // phase 2: A8[g] = Q(dinv_g * (h1[g] @ W2)) -> layer-2 rows carry dinv_src
    if (act) {
        float a2[8];
#pragma unroll
        for (int j = 0; j < 8; ++j) a2[j] = 0.0f;
#pragma unroll 4
        for (int k = 0; k < 32; ++k) {
            float h = sh1[nl][k];
            const float* wr = sW2 + k * 32 + fq;
#pragma unroll
            for (int j = 0; j < 8; ++j) a2[j] += h * wr[j];
        }
#pragma unroll
        for (int j = 0; j < 8; ++j) a2[j] *= dig;
        ((uint2*)(A8 + ((size_t)g << 5)))[lane] = enc8(a2);
    }
}

// ===== layer 2 gather + MFMA head fused: h2 never round-trips through HBM =====
// h1 row (head-phase input) prefetched at entry -- latency hides under the gather.

__global__ __launch_bounds__(256) void k_g2head(
        const unsigned* __restrict__ recs4, const int* __restrict__ pstart,
        const int* __restrict__ pcnt, const float* __restrict__ dinv,
        const unsigned char* __restrict__ A8,
        const float* __restrict__ bias, const float* __restrict__ bnsc,
        const float* __restrict__ bnsh,
        const __half* __restrict__ skiph, const float* __restrict__ x,
        const __half* __restrict__ wp1, const __half* __restrict__ wp2,
        const float* __restrict__ bsum1, const float* __restrict__ bsum2,
        const float* __restrict__ lw, const float* __restrict__ lb,
        float* __restrict__ out, int n) {
    __shared__ __align__(16) __half h2s[64][40];
    __shared__ __align__(16) __half H1lds[4 * 16 * 40];
    int tid = threadIdx.x;
    int nl = tid >> 2;
    int g = blockIdx.x * 64 + nl;
    int lane = tid & 3;
    int fq = lane * 8;
    bool act = g < n;

    // head-phase coordinates + early h1 prefetch (used only after the gather)
    int w = tid >> 6, l = tid & 63;
    int quad = l >> 4, c = l & 15;
    int node_base = blockIdx.x * 64 + w * 16;
    int arow = node_base + c; if (arow > n - 1) arow = n - 1;
    int lr = arow - blockIdx.x * 64;
    half8 a0 = *(const half8*)(skiph + (size_t)arow * 32 + quad * 8);  // h1

    // hoisted per-node scalars + self row
    float dig = 0.0f;
    int cn = 0;
    const unsigned* r = recs4;
    uint2 sr = make_uint2(0u, 0u);
    if (act) {
        dig = dinv[g];
        cn = pcnt[g];
        r = recs4 + pstart[g];
        sr = ((const uint2*)(A8 + ((size_t)g << 5)))[lane];
    }

    // ---------------- gather phase (h2 = GCN2 output) ----------------
    float acc[8];
#pragma unroll
    for (int k = 0; k < 8; ++k) acc[k] = 0.0f;

    if (act) {
        {
            // self-loop: dinv_g * A8hat[g] = dinv_g^2 * A[g]
            float f[8];
            dec8(sr, f);
#pragma unroll
            for (int k = 0; k < 8; ++k) acc[k] = dig * f[k];
        }

        const float qs = 1.0f / WQ14;
        uint4 na, nb;
        if (8 <= cn) { na = *(const uint4*)(r); nb = *(const uint4*)(r + 4); }
        int e = 0;
        for (; e + 8 <= cn; e += 8) {
            uint4 ua = na, ub = nb;
            if (e + 16 <= cn) { na = *(const uint4*)(r + e + 8); nb = *(const uint4*)(r + e + 12); }
            unsigned u[8] = {ua.x, ua.y, ua.z, ua.w, ub.x, ub.y, ub.z, ub.w};
            uint2 rw[8];
#pragma unroll
            for (int q = 0; q < 8; ++q)
                rw[q] = ((const uint2*)(A8 + ((size_t)(u[q] >> 14) << 5)))[lane];
            float nm[8];
#pragma unroll
            for (int q = 0; q < 8; ++q)
                nm[q] = (float)(u[q] & 16383u) * qs;
#pragma unroll
            for (int q = 0; q < 8; ++q) {
                float f[8];
                dec8(rw[q], f);
#pragma unroll
                for (int k = 0; k < 8; ++k) acc[k] += nm[q] * f[k];
            }
        }
        for (; e < cn; ++e) {
            unsigned u0 = r[e];
            uint2 r0 = ((const uint2*)(A8 + ((size_t)(u0 >> 14) << 5)))[lane];
            float n0 = (float)(u0 & 16383u) * qs;
            float f0[8];
            dec8(r0, f0);
#pragma unroll
            for (int k = 0; k < 8; ++k) acc[k] += n0 * f0[k];
        }

        // epilogue: bias + relu + folded BN -> h2 into LDS
        union { __half h[8]; uint4 q; } hv;
#pragma unroll
        for (int k = 0; k < 8; ++k) {
            float v = fmaxf(acc[k] + bias[fq + k], 0.0f);
            hv.h[k] = __float2half(v * bnsc[fq + k] + bnsh[fq + k]);
        }
        *(uint4*)(&h2s[nl][fq]) = hv.q;
    }
    __syncthreads();

    // ---------------- head phase (LSTM1 + LSTM2 + linear) ----------------
    half8 a1 = *(const half8*)(&h2s[lr][quad * 8]);                    // h2 (LDS)

    const half8* b1 = (const half8*)wp1;
    f32x4 d[6];
#pragma unroll
    for (int t = 0; t < 6; ++t) {
        f32x4 ac = {0.0f, 0.0f, 0.0f, 0.0f};
        ac = __builtin_amdgcn_mfma_f32_16x16x32_f16(a0, b1[(t * 2 + 0) * 64 + l], ac, 0, 0, 0);
        ac = __builtin_amdgcn_mfma_f32_16x16x32_f16(a1, b1[(t * 2 + 1) * 64 + l], ac, 0, 0, 0);
        d[t] = ac;
    }

    float bi0 = bsum1[c],      bi1 = bsum1[16 + c];
    float bg0 = bsum1[64 + c], bg1 = bsum1[80 + c];
    float bo0 = bsum1[96 + c], bo1 = bsum1[112 + c];
    float lwc0 = lw[c], lwc1 = lw[c + 16];

    float pa[4];
#pragma unroll
    for (int r2 = 0; r2 < 4; ++r2) {
        float cc0 = fsig(d[0][r2] + bi0) * ftanh(d[2][r2] + bg0);
        float h0 = fsig(d[4][r2] + bo0) * ftanh(cc0);
        float cc1 = fsig(d[1][r2] + bi1) * ftanh(d[3][r2] + bg1);
        float h1 = fsig(d[5][r2] + bo1) * ftanh(cc1);
        pa[r2] = fmaxf(h0, 0.0f) * lwc0 + fmaxf(h1, 0.0f) * lwc1;
        __half* hp = H1lds + (w * 16 + quad * 4 + r2) * 40;
        hp[c] = __float2half(h0);
        hp[c + 16] = __float2half(h1);
    }
    __syncthreads();

    half8 a2 = *(const half8*)(H1lds + (w * 16 + c) * 40 + quad * 8);

    const half8* b2 = (const half8*)wp2;
    f32x4 e2[6];
#pragma unroll
    for (int t = 0; t < 6; ++t) {
        f32x4 ac = {0.0f, 0.0f, 0.0f, 0.0f};
        e2[t] = __builtin_amdgcn_mfma_f32_16x16x32_f16(a2, b2[t * 64 + l], ac, 0, 0, 0);
    }

    float ci0 = bsum2[c],      ci1 = bsum2[16 + c];
    float cg0 = bsum2[64 + c], cg1 = bsum2[80 + c];
    float co0 = bsum2[96 + c], co1 = bsum2[112 + c];
    float lw2c0 = lw[32 + c], lw2c1 = lw[48 + c];
#pragma unroll
    for (int r2 = 0; r2 < 4; ++r2) {
        float cc0 = fsig(e2[0][r2] + ci0) * ftanh(e2[2][r2] + cg0);
        float h0 = fsig(e2[4][r2] + co0) * ftanh(cc0);
        float cc1 = fsig(e2[1][r2] + ci1) * ftanh(e2[3][r2] + cg1);
        float h1 = fsig(e2[5][r2] + co1) * ftanh(cc1);
        pa[r2] += fmaxf(h0, 0.0f) * lw2c0 + fmaxf(h1, 0.0f) * lw2c1;
    }

#pragma unroll
    for (int m = 1; m < 16; m <<= 1) {
#pragma unroll
        for (int r2 = 0; r2 < 4; ++r2) pa[r2] += __shfl_xor(pa[r2], m, 64);
    }

    if (c < 4) {
        int node = node_base + quad * 4 + c;
        if (node < n) {
            const float4 xv = *(const float4*)(x + (size_t)node * 4);
            out[node] = pa[c] + lb[0]
                + fmaxf(xv.x, 0.0f) * lw[64] + fmaxf(xv.y, 0.0f) * lw[65]
                + fmaxf(xv.z, 0.0f) * lw[66] + fmaxf(xv.w, 0.0f) * lw[67];
        }
    }
}

// ================= fallback (atomic scatter, fp32) =================

__global__ void k_initdeg(float* __restrict__ deg, int n) {
    int i = blockIdx.x * blockDim.x + threadIdx.x;
    if (i < n) deg[i] = 1.0f;
}

__global__ void k_deg_only(const int* __restrict__ dst, const float* __restrict__ ew,
                           float* __restrict__ deg, int E) {
    int e = blockIdx.x * blockDim.x + threadIdx.x;
    if (e < E) atomicAdd(&deg[dst[e]], ew[e]);
}

__global__ void k_dinv_f(float* __restrict__ deg, int n) {
    int i = blockIdx.x * blockDim.x + threadIdx.x;
    if (i < n) {
        float d = deg[i];
        deg[i] = d > 0.0f ? rsqrtf(d) : 0.0f;
    }
}

__global__ void k_xw1_f(const float* __restrict__ x, const float* __restrict__ W,
                        float* __restrict__ out, int n) {
    int idx = blockIdx.x * blockDim.x + threadIdx.x;
    if (idx >= n * HF) return;
    int nn = idx >> 5, f = idx & 31;
    const float4 xr = *(const float4*)(x + (size_t)nn * 4);
    out[idx] = xr.x * W[f] + xr.y * W[32 + f] + xr.z * W[64 + f] + xr.w * W[96 + f];
}

__global__ void k_xw2_f(const float* __restrict__ Hin, const float* __restrict__ W,
                        float* __restrict__ out, int n) {
    __shared__ float sW[32 * 32];
    __shared__ float sH[8][32];
    int tid = threadIdx.x;
    for (int i = tid; i < 1024; i += 256) sW[i] = W[i];
    int r = tid >> 5, f = tid & 31;
    int nn = blockIdx.x * 8 + r;
    if (nn < n) sH[r][f] = Hin[(size_t)nn * HF + f];
    __syncthreads();
    if (nn >= n) return;
    float acc = 0.0f;
#pragma unroll
    for (int k = 0; k < 32; ++k) acc += sH[r][k] * sW[k * 32 + f];
    out[(size_t)nn * HF + f] = acc;
}

__global__ void k_selfloop(const float* __restrict__ A, const float* __restrict__ dinv,
                           float* __restrict__ B, int n) {
    int idx = blockIdx.x * blockDim.x + threadIdx.x;
    if (idx >= n * HF) return;
    int nn = idx >> 5;
    float di = dinv[nn];
    B[idx] = di * di * A[idx];
}

__global__ void k_scatter(const int* __restrict__ src, const int* __restrict__ dst,
                          const float* __restrict__ ew, const float* __restrict__ dinv,
                          const float* __restrict__ A, float* __restrict__ B, int total) {
    int idx = blockIdx.x * blockDim.x + threadIdx.x;
    if (idx >= total) return;
    int e = idx >> 5, f = idx & 31;
    int s = src[e], d = dst[e];
    float norm = dinv[s] * ew[e] * dinv[d];
    atomicAdd(&B[d * HF + f], norm * A[s * HF + f]);
}

__global__ void k_post(const float* __restrict__ B, const float* __restrict__ bias,
                       const float* __restrict__ gamma, const float* __restrict__ beta,
                       const float* __restrict__ mean, const float* __restrict__ var,
                       float* __restrict__ Hout, int n) {
    int idx = blockIdx.x * blockDim.x + threadIdx.x;
    if (idx >= n * HF) return;
    int f = idx & 31;
    float v = fmaxf(B[idx] + bias[f], 0.0f);
    float sc = gamma[f] * rsqrtf(var[f] + BN_EPS);
    Hout[idx] = (v - mean[f]) * sc + beta[f];
}

__global__ __launch_bounds__(256) void k_head(
        const float* __restrict__ h1, const float* __restrict__ h2,
        const float* __restrict__ x,
        const float* __restrict__ wih1, const float* __restrict__ bih1, const float* __restrict__ bhh1,
        const float* __restrict__ wih2, const float* __restrict__ bih2, const float* __restrict__ bhh2,
        const float* __restrict__ lw, const float* __restrict__ lb,
        float* __restrict__ out, int n) {
    __shared__ float sH1[32 * 256];
    int tid = threadIdx.x;
    int nn = blockIdx.x * 256 + tid;
    if (nn >= n) return;

    const float4* a = (const float4*)(h1 + (size_t)nn * HF);
    const float4* b = (const float4*)(h2 + (size_t)nn * HF);
    float skip[64];
#pragma unroll
    for (int q = 0; q < 8; ++q) {
        float4 v = a[q];
        skip[4 * q] = v.x; skip[4 * q + 1] = v.y; skip[4 * q + 2] = v.z; skip[4 * q + 3] = v.w;
        float4 u = b[q];
        skip[32 + 4 * q] = u.x; skip[33 + 4 * q] = u.y; skip[34 + 4 * q] = u.z; skip[35 + 4 * q] = u.w;
    }

    float oa = lb[0];
#pragma unroll 1
    for (int j = 0; j < 32; ++j) {
        const float4* wi = (const float4*)(wih1 + (size_t)j * 64);
        const float4* wg = (const float4*)(wih1 + (size_t)(64 + j) * 64);
        const float4* wo = (const float4*)(wih1 + (size_t)(96 + j) * 64);
        float gi = bih1[j] + bhh1[j];
        float gg = bih1[64 + j] + bhh1[64 + j];
        float go = bih1[96 + j] + bhh1[96 + j];
#pragma unroll
        for (int q = 0; q < 16; ++q) {
            float4 aa = wi[q], bb = wg[q], cc4 = wo[q];
            float s0 = skip[4 * q], s1 = skip[4 * q + 1], s2 = skip[4 * q + 2], s3 = skip[4 * q + 3];
            gi += aa.x * s0 + aa.y * s1 + aa.z * s2 + aa.w * s3;
            gg += bb.x * s0 + bb.y * s1 + bb.z * s2 + bb.w * s3;
            go += cc4.x * s0 + cc4.y * s1 + cc4.z * s2 + cc4.w * s3;
        }
        float cc = fsig(gi) * ftanh(gg);
        float hh = fsig(go) * ftanh(cc);
        sH1[j * 256 + tid] = hh;
        oa += fmaxf(hh, 0.0f) * lw[j];
    }

#pragma unroll 1
    for (int j = 0; j < 32; ++j) {
        const float4* wi = (const float4*)(wih2 + (size_t)j * 32);
        const float4* wg = (const float4*)(wih2 + (size_t)(64 + j) * 32);
        const float4* wo = (const float4*)(wih2 + (size_t)(96 + j) * 32);
        float gi = bih2[j] + bhh2[j];
        float gg = bih2[64 + j] + bhh2[64 + j];
        float go = bih2[96 + j] + bhh2[96 + j];
#pragma unroll
        for (int q = 0; q < 8; ++q) {
            float4 aa = wi[q], bb = wg[q], cc4 = wo[q];
            float s0 = sH1[(4 * q) * 256 + tid], s1 = sH1[(4 * q + 1) * 256 + tid];
            float s2 = sH1[(4 * q + 2) * 256 + tid], s3 = sH1[(4 * q + 3) * 256 + tid];
            gi += aa.x * s0 + aa.y * s1 + aa.z * s2 + aa.w * s3;
            gg += bb.x * s0 + bb.y * s1 + bb.z * s2 + bb.w * s3;
            go += cc4.x * s0 + cc4.y * s1 + cc4.z * s2 + cc4.w * s3;
        }
        float cc = fsig(gi) * ftanh(gg);
        float hh = fsig(go) * ftanh(cc);
        oa += fmaxf(hh, 0.0f) * lw[32 + j];
    }

    const float4 xv = *(const float4*)(x + (size_t)nn * 4);
    oa += fmaxf(xv.x, 0.0f) * lw[64] + fmaxf(xv.y, 0.0f) * lw[65] +
          fmaxf(xv.z, 0.0f) * lw[66] + fmaxf(xv.w, 0.0f) * lw[67];
    out[nn] = oa;
}

// ================= launch =================

extern "C" void kernel_launch(void* const* d_in, const int* in_sizes, int n_in,
                              void* d_out, int out_size, void* d_ws, size_t ws_size,
                              hipStream_t stream) {
    const float* x   = (const float*)d_in[0];
    const int*   ei  = (const int*)d_in[1];
    const float* ew  = (const float*)d_in[2];
    const float* g1w = (const float*)d_in[3];
    const float* g1b = (const float*)d_in[4];
    const float* g2w = (const float*)d_in[5];
    const float* g2b = (const float*)d_in[6];
    const float* bn1g = (const float*)d_in[7];
    const float* bn1b = (const float*)d_in[8];
    const float* bn1m = (const float*)d_in[9];
    const float* bn1v = (const float*)d_in[10];
    const float* bn2g = (const float*)d_in[11];
    const float* bn2b = (const float*)d_in[12];
    const float* bn2m = (const float*)d_in[13];
    const float* bn2v = (const float*)d_in[14];
    const float* w1ih = (const float*)d_in[15];
    const float* b1ih = (const float*)d_in[17];
    const float* b1hh = (const float*)d_in[18];
    const float* w2ih = (const float*)d_in[19];
    const float* b2ih = (const float*)d_in[21];
    const float* b2hh = (const float*)d_in[22];
    const float* lw   = (const float*)d_in[23];
    const float* lb   = (const float*)d_in[24];
    float* out = (float*)d_out;

    const int N = in_sizes[0] / 4;
    const int E = in_sizes[2];
    const int* src = ei;
    const int* dst = ei + E;

    const int T = 256;
    const int NB = (N + BS - 1) / BS;
    long long meanb = ((long long)BS * E) / (N > 0 ? N : 1);
    int bcap = (int)(meanb + meanb / 4 + 128);
    bcap = (bcap + 3) & ~3;
    int bcap4 = bcap + 3 * BS;  // room for per-node 16B-alignment padding

    // workspace layout (256B-aligned regions)
    char* p = (char*)d_ws;
    auto alloc = [&](size_t bytes) { char* q = p; p += (bytes + 255) & ~(size_t)255; return q; };
    int*      gcur   = (int*)alloc(sizeof(int) * NB);
    uint2*    recs   = (uint2*)alloc(sizeof(uint2) * (size_t)NB * bcap);
    unsigned* recs4  = (unsigned*)alloc(sizeof(unsigned) * (size_t)NB * bcap4);
    float*    dinv   = (float*)alloc(sizeof(float) * N);
    int*      pstart = (int*)alloc(sizeof(int) * N);
    int*      pcnt   = (int*)alloc(sizeof(int) * N);
    unsigned char* y18 = (unsigned char*)alloc((size_t)N * HF);         // fp8 dinv*(x@W1)
    unsigned char* A8  = (unsigned char*)alloc((size_t)N * HF);         // fp8 dinv*(h1@W2)
    __half*   skiph  = (__half*)alloc(sizeof(__half) * (size_t)N * 32); // h1 f16 only
    __half*   wp1    = (__half*)alloc(sizeof(__half) * 6144);
    __half*   wp2    = (__half*)alloc(sizeof(__half) * 3072);
    float*    bsum1  = (float*)alloc(sizeof(float) * 128);
    float*    bsum2  = (float*)alloc(sizeof(float) * 128);
    float*    bnp    = (float*)alloc(sizeof(float) * 128);  // folded BN sc/sh
    size_t need = (size_t)(p - (char*)d_ws);

    int bN  = (N + T - 1) / T;
    int bE  = (E + T - 1) / T;
    int bNF = (N * HF + T - 1) / T;
    int bN8 = (N + 7) / 8;
    int bG  = (N + 63) / 64;
    int bBin = (E + KEDGE - 1) / KEDGE;

    if (ws_size >= need && NB <= MAXNB && N <= (1 << 18) && bcap <= SCAP) {
        // ---- build: memset cursor + bucket scatter + CSR/prep ----
        hipMemsetAsync(gcur, 0, sizeof(int) * NB, stream);
        k_binsort<<<bBin, 512, 0, stream>>>(src, dst, ew, E, NB, bcap, gcur, recs);
        k_sortb<<<NB, 1024, 0, stream>>>(recs, gcur, bcap, bcap4, x, g1w,
                                         recs4, pstart, pcnt, dinv, y18,
                                         w1ih, b1ih, b1hh, w2ih, b2ih, b2hh,
                                         bn1g, bn1b, bn1m, bn1v,
                                         bn2g, bn2b, bn2m, bn2v,
                                         wp1, wp2, bsum1, bsum2, bnp, N);

        // ---- layer 1: fp8 gather over prescaled y1 + fused xw2 -> skiph(h1), A8 ----
        k_g1w2<<<bG, T, 0, stream>>>(recs4, pstart, pcnt, dinv, y18, g2w,
                                     g1b, bnp, bnp + 32, skiph, A8, N);
        // ---- layer 2 gather + MFMA head fused ----
        k_g2head<<<bG, T, 0, stream>>>(recs4, pstart, pcnt, dinv, A8,
                                       g2b, bnp + 64, bnp + 96,
                                       skiph, x, wp1, wp2, bsum1, bsum2,
                                       lw, lb, out, N);
    } else {
        // ---- fallback: atomic scatter, fp32 ----
        size_t Npad = ((size_t)N + 255) & ~(size_t)255;
        float* fdinv = (float*)d_ws;
        float* fA = fdinv + Npad;
        float* fB = fA + (size_t)N * HF;
        float* fC = fB + (size_t)N * HF;
        int bEF = (int)(((long long)E * HF + T - 1) / T);
        int bH = (N + 255) / 256;

        k_initdeg<<<bN, T, 0, stream>>>(fdinv, N);
        k_deg_only<<<bE, T, 0, stream>>>(dst, ew, fdinv, E);
        k_dinv_f<<<bN, T, 0, stream>>>(fdinv, N);

        k_xw1_f<<<bNF, T, 0, stream>>>(x, g1w, fA, N);
        k_selfloop<<<bNF, T, 0, stream>>>(fA, fdinv, fB, N);
        k_scatter<<<bEF, T, 0, stream>>>(src, dst, ew, fdinv, fA, fB, E * HF);
        k_post<<<bNF, T, 0, stream>>>(fB, g1b, bn1g, bn1b, bn1m, bn1v, fC, N);

        k_xw2_f<<<bN8, T, 0, stream>>>(fC, g2w, fA, N);
        k_selfloop<<<bNF, T, 0, stream>>>(fA, fdinv, fB, N);
        k_scatter<<<bEF, T, 0, stream>>>(src, dst, ew, fdinv, fA, fB, E * HF);
        k_post<<<bNF, T, 0, stream>>>(fB, g2b, bn2g, bn2b, bn2m, bn2v, fB, N);

        k_head<<<bH, T, 0, stream>>>(fC, fB, x, w1ih, b1ih, b1hh, w2ih, b2ih, b2hh,
                                     lw, lb, out, N);
    }
}

// Round 13
// 271.693 us; speedup vs baseline: 1.1729x; 1.0809x over previous
//
#include <hip/hip_runtime.h>
#include <hip/hip_fp16.h>
#include <math.h>

#define BN_EPS 1e-5f
#define HF 32          // hidden features
#define BS 256         // nodes per bucket (8-bit dloc)
#define KEDGE 4096     // edges per binsort block (512 thr x 8 edges)
#define MAXNB 800      // max buckets (NB=782 for N=200k)
#define SCAP 5504      // sortb LDS record-stage capacity (44KB)
#define WQ14 16383.0f  // 14-bit norm quantization
#define WQ22 4194303.0f // 22-bit raw-weight quantization (binsort staging)

typedef _Float16 half8 __attribute__((ext_vector_type(8)));
typedef float f32x4 __attribute__((ext_vector_type(4)));
typedef float f32x2 __attribute__((ext_vector_type(2)));

// fast transcendentals (trans pipe)
__device__ __forceinline__ float fsig(float x) {
    return __builtin_amdgcn_rcpf(1.0f + __expf(-x));
}
__device__ __forceinline__ float ftanh(float x) {
    return 1.0f - 2.0f * __builtin_amdgcn_rcpf(1.0f + __expf(2.0f * x));
}

// ---------- fp8 e4m3 (OCP) helpers: HW converters with SW fallback ----------

__device__ __forceinline__ float e4m3_to_f32_sw(unsigned v) {
    unsigned s = v & 0x80u, E = (v >> 3) & 0xFu, m = v & 7u;
    float r = E ? ldexpf((float)(8 + m), (int)E - 10) : ldexpf((float)m, -9);
    return s ? -r : r;
}

__device__ __forceinline__ unsigned f32_to_e4m3_sw(float x) {
    float ax = fabsf(x);
    unsigned s = x < 0.0f ? 0x80u : 0u;
    if (!(ax > 0.0f)) return s;
    if (ax >= 448.0f) return s | 0x7Eu;
    int e;
    float m = frexpf(ax, &e);      // ax = m * 2^e, m in [0.5,1)
    int E = e - 1 + 7;
    if (E >= 1) {
        int q = (int)(m * 16.0f + 0.5f);
        if (q == 16) { q = 8; E += 1; if (E > 15) return s | 0x7Eu; }
        return s | (unsigned)(E << 3) | (unsigned)(q - 8);
    }
    int q = (int)(ax * 512.0f + 0.5f);
    if (q > 7) return s | 0x08u;
    return s | (unsigned)q;
}

__device__ __forceinline__ void dec8(uint2 r, float* f) {
#if __has_builtin(__builtin_amdgcn_cvt_pk_f32_fp8)
    f32x2 p0 = __builtin_amdgcn_cvt_pk_f32_fp8((int)r.x, false);
    f32x2 p1 = __builtin_amdgcn_cvt_pk_f32_fp8((int)r.x, true);
    f32x2 p2 = __builtin_amdgcn_cvt_pk_f32_fp8((int)r.y, false);
    f32x2 p3 = __builtin_amdgcn_cvt_pk_f32_fp8((int)r.y, true);
    f[0] = p0[0]; f[1] = p0[1]; f[2] = p1[0]; f[3] = p1[1];
    f[4] = p2[0]; f[5] = p2[1]; f[6] = p3[0]; f[7] = p3[1];
#else
#pragma unroll
    for (int k = 0; k < 4; ++k) f[k] = e4m3_to_f32_sw((r.x >> (8 * k)) & 0xFFu);
#pragma unroll
    for (int k = 0; k < 4; ++k) f[4 + k] = e4m3_to_f32_sw((r.y >> (8 * k)) & 0xFFu);
#endif
}

__device__ __forceinline__ uint2 enc8(const float* o) {
#if __has_builtin(__builtin_amdgcn_cvt_pk_fp8_f32)
    int w0 = 0, w1 = 0;
    w0 = __builtin_amdgcn_cvt_pk_fp8_f32(o[0], o[1], w0, false);
    w0 = __builtin_amdgcn_cvt_pk_fp8_f32(o[2], o[3], w0, true);
    w1 = __builtin_amdgcn_cvt_pk_fp8_f32(o[4], o[5], w1, false);
    w1 = __builtin_amdgcn_cvt_pk_fp8_f32(o[6], o[7], w1, true);
    return make_uint2((unsigned)w0, (unsigned)w1);
#else
    unsigned a = 0, b = 0;
#pragma unroll
    for (int k = 0; k < 4; ++k) a |= f32_to_e4m3_sw(o[k]) << (8 * k);
#pragma unroll
    for (int k = 0; k < 4; ++k) b |= f32_to_e4m3_sw(o[4 + k]) << (8 * k);
    return make_uint2(a, b);
#endif
}

// ====== gather over a 4-padded record segment (pads are ZEROED records) ======
// r13: the old scalar tail (mean ~3.5 serial record->row round trips per node)
// is gone -- pads decode to nm=0 / row 0 (harmless broadcast). Main 8-batch loop
// + at most one 4-batch. Zero extra registers vs r10 (r11 lesson: VGPRs cost TLP).
__device__ __forceinline__ void gather_seg4(
        const unsigned* __restrict__ r, int cnp,
        const unsigned char* __restrict__ rows, int lane, float* acc) {
    const float qs = 1.0f / WQ14;
    uint4 na, nb;
    if (8 <= cnp) { na = *(const uint4*)(r); nb = *(const uint4*)(r + 4); }
    int e = 0;
    for (; e + 8 <= cnp; e += 8) {
        uint4 ua = na, ub = nb;
        if (e + 16 <= cnp) { na = *(const uint4*)(r + e + 8); nb = *(const uint4*)(r + e + 12); }
        unsigned u[8] = {ua.x, ua.y, ua.z, ua.w, ub.x, ub.y, ub.z, ub.w};
        uint2 rw[8];
#pragma unroll
        for (int q = 0; q < 8; ++q)
            rw[q] = ((const uint2*)(rows + ((size_t)(u[q] >> 14) << 5)))[lane];
        float nm[8];
#pragma unroll
        for (int q = 0; q < 8; ++q)
            nm[q] = (float)(u[q] & 16383u) * qs;
#pragma unroll
        for (int q = 0; q < 8; ++q) {
            float f[8];
            dec8(rw[q], f);
#pragma unroll
            for (int k = 0; k < 8; ++k) acc[k] += nm[q] * f[k];
        }
    }
    if (e < cnp) {   // exactly 4 records remain (cnp is a multiple of 4)
        uint4 ua = *(const uint4*)(r + e);
        unsigned u[4] = {ua.x, ua.y, ua.z, ua.w};
        uint2 rw[4];
#pragma unroll
        for (int q = 0; q < 4; ++q)
            rw[q] = ((const uint2*)(rows + ((size_t)(u[q] >> 14) << 5)))[lane];
        float nm[4];
#pragma unroll
        for (int q = 0; q < 4; ++q)
            nm[q] = (float)(u[q] & 16383u) * qs;
#pragma unroll
        for (int q = 0; q < 4; ++q) {
            float f[8];
            dec8(rw[q], f);
#pragma unroll
            for (int k = 0; k < 8; ++k) acc[k] += nm[q] * f[k];
        }
    }
}

// ================= Phase A: register-staged direct scatter into buckets =================
// r7 lesson: per-block cost scales with NB, so fewer/fatter blocks win (512 thr x 4096).
// Vector loads; record handling compile-time-indexed (r6's runtime loop spilled).

__global__ __launch_bounds__(512) void k_binsort(
        const int* __restrict__ src, const int* __restrict__ dst,
        const float* __restrict__ ew, int E, int NB, int bcap,
        int* __restrict__ gcur, uint2* __restrict__ recs) {
    __shared__ int hist[MAXNB], curs[MAXNB];

    int tid = threadIdx.x;
    int base = blockIdx.x * KEDGE;
    int cnt = min(KEDGE, E - base);

    for (int i = tid; i < NB; i += 512) hist[i] = 0;
    __syncthreads();

    uint2 rec[8];
    int eb = base + tid * 8;
    int rem = cnt - tid * 8;           // edges owned by this thread (<=0 .. 8)
    if (rem >= 8) {                    // fast path: whole-block for non-tail blocks
        int4 s0 = *(const int4*)(src + eb);
        int4 s1 = *(const int4*)(src + eb + 4);
        int4 d0 = *(const int4*)(dst + eb);
        int4 d1 = *(const int4*)(dst + eb + 4);
        float4 w0 = *(const float4*)(ew + eb);
        float4 w1 = *(const float4*)(ew + eb + 4);
        int ss[8] = {s0.x, s0.y, s0.z, s0.w, s1.x, s1.y, s1.z, s1.w};
        int dd[8] = {d0.x, d0.y, d0.z, d0.w, d1.x, d1.y, d1.z, d1.w};
        float ww[8] = {w0.x, w0.y, w0.z, w0.w, w1.x, w1.y, w1.z, w1.w};
#pragma unroll
        for (int k = 0; k < 8; ++k) {
            unsigned q = (unsigned)(ww[k] * WQ22 + 0.5f);
            if (q > 4194303u) q = 4194303u;
            int b = dd[k] >> 8;
            rec[k] = make_uint2(((unsigned)ss[k] << 8) | (unsigned)(dd[k] & 255),
                                ((unsigned)b << 22) | q);
        }
    } else {
#pragma unroll
        for (int k = 0; k < 8; ++k) {
            if (k < rem) {
                int s = src[eb + k];
                int d = dst[eb + k];
                float w = ew[eb + k];
                unsigned q = (unsigned)(w * WQ22 + 0.5f);
                if (q > 4194303u) q = 4194303u;
                int b = d >> 8;
                rec[k] = make_uint2(((unsigned)s << 8) | (unsigned)(d & 255),
                                    ((unsigned)b << 22) | q);
            }
        }
    }
#pragma unroll
    for (int k = 0; k < 8; ++k)
        if (k < rem) atomicAdd(&hist[rec[k].y >> 22], 1);
    __syncthreads();

    // bucket base in global recs region; curs counts up from it
    for (int b = tid; b < NB; b += 512) {
        int len = hist[b];
        curs[b] = len ? atomicAdd(&gcur[b], len) : 0;
    }
    __syncthreads();

#pragma unroll
    for (int k = 0; k < 8; ++k) {
        if (k < rem) {
            uint2 u = rec[k];
            int b = u.y >> 22;
            int off = atomicAdd(&curs[b], 1);
            if (off < bcap) recs[(size_t)b * bcap + off] = u;
        }
    }
}

// ====== Phase B: 4B records (16B-aligned segs, ZEROED pads) + CSR + dinv + y1 ======
// 1024 threads; LDS record staging so the CSR scatter never re-reads 25.6MB of
// global. Block 0 also does the one-time weight pack + bias sums + BN fold
// (bnp: [0:32)=sc1, [32:64)=sh1, [64:96)=sc2, [96:128)=sh2).

__global__ __launch_bounds__(1024) void k_sortb(
        const uint2* __restrict__ recs, const int* __restrict__ gcur,
        int bcap, int bcap4,
        const float* __restrict__ x, const float* __restrict__ W1,
        unsigned* __restrict__ recs4, int* __restrict__ pstart,
        int* __restrict__ pcnt, float* __restrict__ dinv,
        unsigned char* __restrict__ y18,
        const float* __restrict__ wih1, const float* __restrict__ bih1,
        const float* __restrict__ bhh1, const float* __restrict__ wih2,
        const float* __restrict__ bih2, const float* __restrict__ bhh2,
        const float* __restrict__ bn1g, const float* __restrict__ bn1b,
        const float* __restrict__ bn1m, const float* __restrict__ bn1v,
        const float* __restrict__ bn2g, const float* __restrict__ bn2b,
        const float* __restrict__ bn2m, const float* __restrict__ bn2v,
        __half* __restrict__ wp1, __half* __restrict__ wp2,
        float* __restrict__ bsum1, float* __restrict__ bsum2,
        float* __restrict__ bnp, int n) {
    __shared__ uint2 srec[SCAP];
    __shared__ int hist[BS], excl4[BS], curs[BS], wsm[BS];
    __shared__ float sdv[BS];
    __shared__ float sW1[128];

    int b = blockIdx.x, tid = threadIdx.x;
    int cnt = min(gcur[b], bcap);
    const uint2* r = recs + (size_t)b * bcap;
    const float dq = 1.0f / WQ22;

    // one-time prep work (block 0 only; independent of this block's bucket work)
    if (b == 0) {
        const int tg[6] = {0, 16, 64, 80, 96, 112};
        for (int idx = tid; idx < 9600; idx += 1024) {
            if (idx < 6144) {
                int t = idx >> 10, rm = idx & 1023;
                int kc = rm >> 9, rm2 = rm & 511;
                int lane = rm2 >> 3, j = rm2 & 7;
                int g = tg[t] + (lane & 15);
                int k = kc * 32 + (lane >> 4) * 8 + j;
                wp1[idx] = __float2half(wih1[g * 64 + k]);
            } else if (idx < 9216) {
                int i2 = idx - 6144;
                int t = i2 >> 9, rm2 = i2 & 511;
                int lane = rm2 >> 3, j = rm2 & 7;
                int g = tg[t] + (lane & 15);
                int k = (lane >> 4) * 8 + j;
                wp2[i2] = __float2half(wih2[g * 32 + k]);
            } else if (idx < 9344) {
                int i = idx - 9216;
                bsum1[i] = bih1[i] + bhh1[i];
            } else if (idx < 9472) {
                int i = idx - 9344;
                bsum2[i] = bih2[i] + bhh2[i];
            } else {
                int f2 = idx - 9472;        // 0..127
                int f = f2 & 31;
                if (f2 < 32) {
                    bnp[f2] = bn1g[f] * rsqrtf(bn1v[f] + BN_EPS);
                } else if (f2 < 64) {
                    float sc = bn1g[f] * rsqrtf(bn1v[f] + BN_EPS);
                    bnp[f2] = bn1b[f] - bn1m[f] * sc;
                } else if (f2 < 96) {
                    bnp[f2] = bn2g[f] * rsqrtf(bn2v[f] + BN_EPS);
                } else {
                    float sc = bn2g[f] * rsqrtf(bn2v[f] + BN_EPS);
                    bnp[f2] = bn2b[f] - bn2m[f] * sc;
                }
            }
        }
    }

    if (tid < BS) { hist[tid] = 0; wsm[tid] = 0; }
    if (tid >= 256 && tid < 384) sW1[tid - 256] = W1[tid - 256];
    __syncthreads();

    for (int i = tid; i < cnt; i += 1024) {
        uint2 u = r[i];
        if (i < SCAP) srec[i] = u;
        int dl = u.x & 255;
        atomicAdd(&hist[dl], 1);
        atomicAdd(&wsm[dl], (int)(u.y & 4194303u));
    }
    __syncthreads();

    if (tid < BS) {
        int g = b * BS + tid;
        sdv[tid] = (g < n) ? rsqrtf(1.0f + (float)wsm[tid] * dq) : 0.0f;
    }
    // exclusive scan over 4-padded lengths -> 16B-aligned per-node segments
    if (tid < 64) {
        int run = 0;
        for (int c = 0; c < BS; c += 64) {
            int idx = c + tid;
            int v = (hist[idx] + 3) & ~3;
            int incl = v;
#pragma unroll
            for (int o = 1; o < 64; o <<= 1) {
                int up = __shfl_up(incl, o, 64);
                if (tid >= o) incl += up;
            }
            int e = run + incl - v;
            excl4[idx] = e; curs[idx] = e;
            run += __shfl(incl, 63, 64);
        }
    }
    __syncthreads();

    unsigned* out4 = recs4 + (size_t)b * bcap4;
    for (int i = tid; i < cnt; i += 1024) {
        uint2 u = (i < SCAP) ? srec[i] : r[i];
        int dl = u.x & 255;
        int pos = atomicAdd(&curs[dl], 1);
        float qn = (float)(u.y & 4194303u) * dq * sdv[dl];  // w * dinv_d
        unsigned q = (unsigned)(qn * WQ14 + 0.5f);
        if (q > 16383u) q = 16383u;
        out4[pos] = ((u.x >> 8) << 14) | q;
    }

    // y18[g] = Q(dinv_g * (x_g @ W1)): 4 threads/node, 8 features each
    {
        int node = tid >> 2, q = tid & 3;
        int g = b * BS + node;
        if (g < n) {
            float4 xv = *(const float4*)(x + (size_t)g * 4);
            float sc = sdv[node];
            int f0 = q * 8;
            float o[8];
#pragma unroll
            for (int k = 0; k < 8; ++k)
                o[k] = sc * (xv.x * sW1[f0 + k] + xv.y * sW1[32 + f0 + k] +
                             xv.z * sW1[64 + f0 + k] + xv.w * sW1[96 + f0 + k]);
            ((uint2*)(y18 + ((size_t)g << 5)))[q] = enc8(o);
        }
    }

    if (tid < BS) {
        int g = b * BS + tid;
        // ZERO the <=3 pad slots (disjoint from scattered slots -- no race):
        // zero record -> nm=0, row 0 -> contributes nothing in gathers.
        int end = excl4[tid] + hist[tid];
        int pend = excl4[tid] + ((hist[tid] + 3) & ~3);
        for (int p2 = end; p2 < pend; ++p2) out4[p2] = 0u;
        if (g < n) {
            pstart[g] = b * bcap4 + excl4[tid];
            pcnt[g] = hist[tid];
            dinv[g] = sdv[tid];
        }
    }
}

// ====== layer 1: fp8-row gather over prescaled y1 + BN + fused xw2 -> A8, skiph(h1) ======
// r10 operating point (depth-1 prefetch, ~60 VGPR) + r13 padded tail-free loop.

__global__ __launch_bounds__(256) void k_g1w2(
        const unsigned* __restrict__ recs4, const int* __restrict__ pstart,
        const int* __restrict__ pcnt, const float* __restrict__ dinv,
        const unsigned char* __restrict__ y18, const float* __restrict__ W2,
        const float* __restrict__ bias, const float* __restrict__ bnsc,
        const float* __restrict__ bnsh,
        __half* __restrict__ skiph, unsigned char* __restrict__ A8, int n) {
    __shared__ float sW2[1024];
    __shared__ float sh1[64][33];
    int tid = threadIdx.x;

    int nl = tid >> 2;
    int g = blockIdx.x * 64 + nl;
    int lane = tid & 3;
    int fq = lane * 8;
    bool act = g < n;

    // hoisted per-node scalars + self row (latency overlap with sW2 staging)
    float dig = 0.0f;
    int cn = 0;
    const unsigned* r = recs4;
    uint2 sr = make_uint2(0u, 0u);
    if (act) {
        dig = dinv[g];
        cn = pcnt[g];
        r = recs4 + pstart[g];
        sr = ((const uint2*)(y18 + ((size_t)g << 5)))[lane];
    }

    // stage W2 (read only in phase 2 -- no barrier needed here)
    for (int i = tid; i < 1024; i += 256) sW2[i] = W2[i];

    float acc[8];
#pragma unroll
    for (int k = 0; k < 8; ++k) acc[k] = 0.0f;

    if (act) {
        {
            // self-loop: dinv_g * y18hat[g] = dinv_g^2 * y1[g]
            float f[8];
            dec8(sr, f);
#pragma unroll
            for (int k = 0; k < 8; ++k) acc[k] = dig * f[k];
        }
        gather_seg4(r, (cn + 3) & ~3, y18, lane, acc);
    }

    // h1 epilogue: bias + relu + folded BN; stage for xw2; emit fp16 h1 slice
    float o[8];
#pragma unroll
    for (int k = 0; k < 8; ++k) {
        float v = fmaxf(acc[k] + bias[fq + k], 0.0f);
        o[k] = v * bnsc[fq + k] + bnsh[fq + k];
        sh1[nl][fq + k] = o[k];
    }
    if (act) {
        union { __half h[8]; uint4 q; } hv;
#pragma unroll
        for (int k = 0; k < 8; ++k) hv.h[k] = __float2half(o[k]);
        *(uint4*)(skiph + (size_t)g * 32 + fq) = hv.q;
    }
    __syncthreads();

    // phase 2: A8[g] = Q(dinv_g * (h1[g] @ W2)) -> layer-2 rows carry dinv_src
    if (act) {
        float a2[8];
#pragma unroll
        for (int j = 0; j < 8; ++j) a2[j] = 0.0f;
#pragma unroll 4
        for (int k = 0; k < 32; ++k) {
            float h = sh1[nl][k];
            const float* wr = sW2 + k * 32 + fq;
#pragma unroll
            for (int j = 0; j < 8; ++j) a2[j] += h * wr[j];
        }
#pragma unroll
        for (int j = 0; j < 8; ++j) a2[j] *= dig;
        ((uint2*)(A8 + ((size_t)g << 5)))[lane] = enc8(a2);
    }
}

// ===== layer 2 gather + MFMA head fused: h2 never round-trips through HBM =====
// h1 row (head-phase input) prefetched at entry -- latency hides under the gather.

__global__ __launch_bounds__(256) void k_g2head(
        const unsigned* __restrict__ recs4, const int* __restrict__ pstart,
        const int* __restrict__ pcnt, const float* __restrict__ dinv,
        const unsigned char* __restrict__ A8,
        const float* __restrict__ bias, const float* __restrict__ bnsc,
        const float* __restrict__ bnsh,
        const __half* __restrict__ skiph, const float* __restrict__ x,
        const __half* __restrict__ wp1, const __half* __restrict__ wp2,
        const float* __restrict__ bsum1, const float* __restrict__ bsum2,
        const float* __restrict__ lw, const float* __restrict__ lb,
        float* __restrict__ out, int n) {
    __shared__ __align__(16) __half h2s[64][40];
    __shared__ __align__(16) __half H1lds[4 * 16 * 40];
    int tid = threadIdx.x;
    int nl = tid >> 2;
    int g = blockIdx.x * 64 + nl;
    int lane = tid & 3;
    int fq = lane * 8;
    bool act = g < n;

    // head-phase coordinates + early h1 prefetch (used only after the gather)
    int w = tid >> 6, l = tid & 63;
    int quad = l >> 4, c = l & 15;
    int node_base = blockIdx.x * 64 + w * 16;
    int arow = node_base + c; if (arow > n - 1) arow = n - 1;
    int lr = arow - blockIdx.x * 64;
    half8 a0 = *(const half8*)(skiph + (size_t)arow * 32 + quad * 8);  // h1

    // hoisted per-node scalars + self row
    float dig = 0.0f;
    int cn = 0;
    const unsigned* r = recs4;
    uint2 sr = make_uint2(0u, 0u);
    if (act) {
        dig = dinv[g];
        cn = pcnt[g];
        r = recs4 + pstart[g];
        sr = ((const uint2*)(A8 + ((size_t)g << 5)))[lane];
    }

    // ---------------- gather phase (h2 = GCN2 output) ----------------
    float acc[8];
#pragma unroll
    for (int k = 0; k < 8; ++k) acc[k] = 0.0f;

    if (act) {
        {
            // self-loop: dinv_g * A8hat[g] = dinv_g^2 * A[g]
            float f[8];
            dec8(sr, f);
#pragma unroll
            for (int k = 0; k < 8; ++k) acc[k] = dig * f[k];
        }
        gather_seg4(r, (cn + 3) & ~3, A8, lane, acc);

        // epilogue: bias + relu + folded BN -> h2 into LDS
        union { __half h[8]; uint4 q; } hv;
#pragma unroll
        for (int k = 0; k < 8; ++k) {
            float v = fmaxf(acc[k] + bias[fq + k], 0.0f);
            hv.h[k] = __float2half(v * bnsc[fq + k] + bnsh[fq + k]);
        }
        *(uint4*)(&h2s[nl][fq]) = hv.q;
    }
    __syncthreads();

    // ---------------- head phase (LSTM1 + LSTM2 + linear) ----------------
    half8 a1 = *(const half8*)(&h2s[lr][quad * 8]);                    // h2 (LDS)

    const half8* b1 = (const half8*)wp1;
    f32x4 d[6];
#pragma unroll
    for (int t = 0; t < 6; ++t) {
        f32x4 ac = {0.0f, 0.0f, 0.0f, 0.0f};
        ac = __builtin_amdgcn_mfma_f32_16x16x32_f16(a0, b1[(t * 2 + 0) * 64 + l], ac, 0, 0, 0);
        ac = __builtin_amdgcn_mfma_f32_16x16x32_f16(a1, b1[(t * 2 + 1) * 64 + l], ac, 0, 0, 0);
        d[t] = ac;
    }

    float bi0 = bsum1[c],      bi1 = bsum1[16 + c];
    float bg0 = bsum1[64 + c], bg1 = bsum1[80 + c];
    float bo0 = bsum1[96 + c], bo1 = bsum1[112 + c];
    float lwc0 = lw[c], lwc1 = lw[c + 16];

    float pa[4];
#pragma unroll
    for (int r2 = 0; r2 < 4; ++r2) {
        float cc0 = fsig(d[0][r2] + bi0) * ftanh(d[2][r2] + bg0);
        float h0 = fsig(d[4][r2] + bo0) * ftanh(cc0);
        float cc1 = fsig(d[1][r2] + bi1) * ftanh(d[3][r2] + bg1);
        float h1 = fsig(d[5][r2] + bo1) * ftanh(cc1);
        pa[r2] = fmaxf(h0, 0.0f) * lwc0 + fmaxf(h1, 0.0f) * lwc1;
        __half* hp = H1lds + (w * 16 + quad * 4 + r2) * 40;
        hp[c] = __float2half(h0);
        hp[c + 16] = __float2half(h1);
    }
    __syncthreads();

    half8 a2 = *(const half8*)(H1lds + (w * 16 + c) * 40 + quad * 8);

    const half8* b2 = (const half8*)wp2;
    f32x4 e2[6];
#pragma unroll
    for (int t = 0; t < 6; ++t) {
        f32x4 ac = {0.0f, 0.0f, 0.0f, 0.0f};
        e2[t] = __builtin_amdgcn_mfma_f32_16x16x32_f16(a2, b2[t * 64 + l], ac, 0, 0, 0);
    }

    float ci0 = bsum2[c],      ci1 = bsum2[16 + c];
    float cg0 = bsum2[64 + c], cg1 = bsum2[80 + c];
    float co0 = bsum2[96 + c], co1 = bsum2[112 + c];
    float lw2c0 = lw[32 + c], lw2c1 = lw[48 + c];
#pragma unroll
    for (int r2 = 0; r2 < 4; ++r2) {
        float cc0 = fsig(e2[0][r2] + ci0) * ftanh(e2[2][r2] + cg0);
        float h0 = fsig(e2[4][r2] + co0) * ftanh(cc0);
        float cc1 = fsig(e2[1][r2] + ci1) * ftanh(e2[3][r2] + cg1);
        float h1 = fsig(e2[5][r2] + co1) * ftanh(cc1);
        pa[r2] += fmaxf(h0, 0.0f) * lw2c0 + fmaxf(h1, 0.0f) * lw2c1;
    }

#pragma unroll
    for (int m = 1; m < 16; m <<= 1) {
#pragma unroll
        for (int r2 = 0; r2 < 4; ++r2) pa[r2] += __shfl_xor(pa[r2], m, 64);
    }

    if (c < 4) {
        int node = node_base + quad * 4 + c;
        if (node < n) {
            const float4 xv = *(const float4*)(x + (size_t)node * 4);
            out[node] = pa[c] + lb[0]
                + fmaxf(xv.x, 0.0f) * lw[64] + fmaxf(xv.y, 0.0f) * lw[65]
                + fmaxf(xv.z, 0.0f) * lw[66] + fmaxf(xv.w, 0.0f) * lw[67];
        }
    }
}

// ================= fallback (atomic scatter, fp32) =================

__global__ void k_initdeg(float* __restrict__ deg, int n) {
    int i = blockIdx.x * blockDim.x + threadIdx.x;
    if (i < n) deg[i] = 1.0f;
}

__global__ void k_deg_only(const int* __restrict__ dst, const float* __restrict__ ew,
                           float* __restrict__ deg, int E) {
    int e = blockIdx.x * blockDim.x + threadIdx.x;
    if (e < E) atomicAdd(&deg[dst[e]], ew[e]);
}

__global__ void k_dinv_f(float* __restrict__ deg, int n) {
    int i = blockIdx.x * blockDim.x + threadIdx.x;
    if (i < n) {
        float d = deg[i];
        deg[i] = d > 0.0f ? rsqrtf(d) : 0.0f;
    }
}

__global__ void k_xw1_f(const float* __restrict__ x, const float* __restrict__ W,
                        float* __restrict__ out, int n) {
    int idx = blockIdx.x * blockDim.x + threadIdx.x;
    if (idx >= n * HF) return;
    int nn = idx >> 5, f = idx & 31;
    const float4 xr = *(const float4*)(x + (size_t)nn * 4);
    out[idx] = xr.x * W[f] + xr.y * W[32 + f] + xr.z * W[64 + f] + xr.w * W[96 + f];
}

__global__ void k_xw2_f(const float* __restrict__ Hin, const float* __restrict__ W,
                        float* __restrict__ out, int n) {
    __shared__ float sW[32 * 32];
    __shared__ float sH[8][32];
    int tid = threadIdx.x;
    for (int i = tid; i < 1024; i += 256) sW[i] = W[i];
    int r = tid >> 5, f = tid & 31;
    int nn = blockIdx.x * 8 + r;
    if (nn < n) sH[r][f] = Hin[(size_t)nn * HF + f];
    __syncthreads();
    if (nn >= n) return;
    float acc = 0.0f;
#pragma unroll
    for (int k = 0; k < 32; ++k) acc += sH[r][k] * sW[k * 32 + f];
    out[(size_t)nn * HF + f] = acc;
}

__global__ void k_selfloop(const float* __restrict__ A, const float* __restrict__ dinv,
                           float* __restrict__ B, int n) {
    int idx = blockIdx.x * blockDim.x + threadIdx.x;
    if (idx >= n * HF) return;
    int nn = idx >> 5;
    float di = dinv[nn];
    B[idx] = di * di * A[idx];
}

__global__ void k_scatter(const int* __restrict__ src, const int* __restrict__ dst,
                          const float* __restrict__ ew, const float* __restrict__ dinv,
                          const float* __restrict__ A, float* __restrict__ B, int total) {
    int idx = blockIdx.x * blockDim.x + threadIdx.x;
    if (idx >= total) return;
    int e = idx >> 5, f = idx & 31;
    int s = src[e], d = dst[e];
    float norm = dinv[s] * ew[e] * dinv[d];
    atomicAdd(&B[d * HF + f], norm * A[s * HF + f]);
}

__global__ void k_post(const float* __restrict__ B, const float* __restrict__ bias,
                       const float* __restrict__ gamma, const float* __restrict__ beta,
                       const float* __restrict__ mean, const float* __restrict__ var,
                       float* __restrict__ Hout, int n) {
    int idx = blockIdx.x * blockDim.x + threadIdx.x;
    if (idx >= n * HF) return;
    int f = idx & 31;
    float v = fmaxf(B[idx] + bias[f], 0.0f);
    float sc = gamma[f] * rsqrtf(var[f] + BN_EPS);
    Hout[idx] = (v - mean[f]) * sc + beta[f];
}

__global__ __launch_bounds__(256) void k_head(
        const float* __restrict__ h1, const float* __restrict__ h2,
        const float* __restrict__ x,
        const float* __restrict__ wih1, const float* __restrict__ bih1, const float* __restrict__ bhh1,
        const float* __restrict__ wih2, const float* __restrict__ bih2, const float* __restrict__ bhh2,
        const float* __restrict__ lw, const float* __restrict__ lb,
        float* __restrict__ out, int n) {
    __shared__ float sH1[32 * 256];
    int tid = threadIdx.x;
    int nn = blockIdx.x * 256 + tid;
    if (nn >= n) return;

    const float4* a = (const float4*)(h1 + (size_t)nn * HF);
    const float4* b = (const float4*)(h2 + (size_t)nn * HF);
    float skip[64];
#pragma unroll
    for (int q = 0; q < 8; ++q) {
        float4 v = a[q];
        skip[4 * q] = v.x; skip[4 * q + 1] = v.y; skip[4 * q + 2] = v.z; skip[4 * q + 3] = v.w;
        float4 u = b[q];
        skip[32 + 4 * q] = u.x; skip[33 + 4 * q] = u.y; skip[34 + 4 * q] = u.z; skip[35 + 4 * q] = u.w;
    }

    float oa = lb[0];
#pragma unroll 1
    for (int j = 0; j < 32; ++j) {
        const float4* wi = (const float4*)(wih1 + (size_t)j * 64);
        const float4* wg = (const float4*)(wih1 + (size_t)(64 + j) * 64);
        const float4* wo = (const float4*)(wih1 + (size_t)(96 + j) * 64);
        float gi = bih1[j] + bhh1[j];
        float gg = bih1[64 + j] + bhh1[64 + j];
        float go = bih1[96 + j] + bhh1[96 + j];
#pragma unroll
        for (int q = 0; q < 16; ++q) {
            float4 aa = wi[q], bb = wg[q], cc4 = wo[q];
            float s0 = skip[4 * q], s1 = skip[4 * q + 1], s2 = skip[4 * q + 2], s3 = skip[4 * q + 3];
            gi += aa.x * s0 + aa.y * s1 + aa.z * s2 + aa.w * s3;
            gg += bb.x * s0 + bb.y * s1 + bb.z * s2 + bb.w * s3;
            go += cc4.x * s0 + cc4.y * s1 + cc4.z * s2 + cc4.w * s3;
        }
        float cc = fsig(gi) * ftanh(gg);
        float hh = fsig(go) * ftanh(cc);
        sH1[j * 256 + tid] = hh;
        oa += fmaxf(hh, 0.0f) * lw[j];
    }

#pragma unroll 1
    for (int j = 0; j < 32; ++j) {
        const float4* wi = (const float4*)(wih2 + (size_t)j * 32);
        const float4* wg = (const float4*)(wih2 + (size_t)(64 + j) * 32);
        const float4* wo = (const float4*)(wih2 + (size_t)(96 + j) * 32);
        float gi = bih2[j] + bhh2[j];
        float gg = bih2[64 + j] + bhh2[64 + j];
        float go = bih2[96 + j] + bhh2[96 + j];
#pragma unroll
        for (int q = 0; q < 8; ++q) {
            float4 aa = wi[q], bb = wg[q], cc4 = wo[q];
            float s0 = sH1[(4 * q) * 256 + tid], s1 = sH1[(4 * q + 1) * 256 + tid];
            float s2 = sH1[(4 * q + 2) * 256 + tid], s3 = sH1[(4 * q + 3) * 256 + tid];
            gi += aa.x * s0 + aa.y * s1 + aa.z * s2 + aa.w * s3;
            gg += bb.x * s0 + bb.y * s1 + bb.z * s2 + bb.w * s3;
            go += cc4.x * s0 + cc4.y * s1 + cc4.z * s2 + cc4.w * s3;
        }
        float cc = fsig(gi) * ftanh(gg);
        float hh = fsig(go) * ftanh(cc);
        oa += fmaxf(hh, 0.0f) * lw[32 + j];
    }

    const float4 xv = *(const float4*)(x + (size_t)nn * 4);
    oa += fmaxf(xv.x, 0.0f) * lw[64] + fmaxf(xv.y, 0.0f) * lw[65] +
          fmaxf(xv.z, 0.0f) * lw[66] + fmaxf(xv.w, 0.0f) * lw[67];
    out[nn] = oa;
}

// ================= launch =================

extern "C" void kernel_launch(void* const* d_in, const int* in_sizes, int n_in,
                              void* d_out, int out_size, void* d_ws, size_t ws_size,
                              hipStream_t stream) {
    const float* x   = (const float*)d_in[0];
    const int*   ei  = (const int*)d_in[1];
    const float* ew  = (const float*)d_in[2];
    const float* g1w = (const float*)d_in[3];
    const float* g1b = (const float*)d_in[4];
    const float* g2w = (const float*)d_in[5];
    const float* g2b = (const float*)d_in[6];
    const float* bn1g = (const float*)d_in[7];
    const float* bn1b = (const float*)d_in[8];
    const float* bn1m = (const float*)d_in[9];
    const float* bn1v = (const float*)d_in[10];
    const float* bn2g = (const float*)d_in[11];
    const float* bn2b = (const float*)d_in[12];
    const float* bn2m = (const float*)d_in[13];
    const float* bn2v = (const float*)d_in[14];
    const float* w1ih = (const float*)d_in[15];
    const float* b1ih = (const float*)d_in[17];
    const float* b1hh = (const float*)d_in[18];
    const float* w2ih = (const float*)d_in[19];
    const float* b2ih = (const float*)d_in[21];
    const float* b2hh = (const float*)d_in[22];
    const float* lw   = (const float*)d_in[23];
    const float* lb   = (const float*)d_in[24];
    float* out = (float*)d_out;

    const int N = in_sizes[0] / 4;
    const int E = in_sizes[2];
    const int* src = ei;
    const int* dst = ei + E;

    const int T = 256;
    const int NB = (N + BS - 1) / BS;
    long long meanb = ((long long)BS * E) / (N > 0 ? N : 1);
    int bcap = (int)(meanb + meanb / 4 + 128);
    bcap = (bcap + 3) & ~3;
    int bcap4 = bcap + 3 * BS;  // room for per-node 16B-alignment padding

    // workspace layout (256B-aligned regions)
    char* p = (char*)d_ws;
    auto alloc = [&](size_t bytes) { char* q = p; p += (bytes + 255) & ~(size_t)255; return q; };
    int*      gcur   = (int*)alloc(sizeof(int) * NB);
    uint2*    recs   = (uint2*)alloc(sizeof(uint2) * (size_t)NB * bcap);
    unsigned* recs4  = (unsigned*)alloc(sizeof(unsigned) * (size_t)NB * bcap4);
    float*    dinv   = (float*)alloc(sizeof(float) * N);
    int*      pstart = (int*)alloc(sizeof(int) * N);
    int*      pcnt   = (int*)alloc(sizeof(int) * N);
    unsigned char* y18 = (unsigned char*)alloc((size_t)N * HF);         // fp8 dinv*(x@W1)
    unsigned char* A8  = (unsigned char*)alloc((size_t)N * HF);         // fp8 dinv*(h1@W2)
    __half*   skiph  = (__half*)alloc(sizeof(__half) * (size_t)N * 32); // h1 f16 only
    __half*   wp1    = (__half*)alloc(sizeof(__half) * 6144);
    __half*   wp2    = (__half*)alloc(sizeof(__half) * 3072);
    float*    bsum1  = (float*)alloc(sizeof(float) * 128);
    float*    bsum2  = (float*)alloc(sizeof(float) * 128);
    float*    bnp    = (float*)alloc(sizeof(float) * 128);  // folded BN sc/sh
    size_t need = (size_t)(p - (char*)d_ws);

    int bN  = (N + T - 1) / T;
    int bE  = (E + T - 1) / T;
    int bNF = (N * HF + T - 1) / T;
    int bN8 = (N + 7) / 8;
    int bG  = (N + 63) / 64;
    int bBin = (E + KEDGE - 1) / KEDGE;

    if (ws_size >= need && NB <= MAXNB && N <= (1 << 18) && bcap <= SCAP) {
        // ---- build: memset cursor + bucket scatter + CSR/prep ----
        hipMemsetAsync(gcur, 0, sizeof(int) * NB, stream);
        k_binsort<<<bBin, 512, 0, stream>>>(src, dst, ew, E, NB, bcap, gcur, recs);
        k_sortb<<<NB, 1024, 0, stream>>>(recs, gcur, bcap, bcap4, x, g1w,
                                         recs4, pstart, pcnt, dinv, y18,
                                         w1ih, b1ih, b1hh, w2ih, b2ih, b2hh,
                                         bn1g, bn1b, bn1m, bn1v,
                                         bn2g, bn2b, bn2m, bn2v,
                                         wp1, wp2, bsum1, bsum2, bnp, N);

        // ---- layer 1: fp8 gather over prescaled y1 + fused xw2 -> skiph(h1), A8 ----
        k_g1w2<<<bG, T, 0, stream>>>(recs4, pstart, pcnt, dinv, y18, g2w,
                                     g1b, bnp, bnp + 32, skiph, A8, N);
        // ---- layer 2 gather + MFMA head fused ----
        k_g2head<<<bG, T, 0, stream>>>(recs4, pstart, pcnt, dinv, A8,
                                       g2b, bnp + 64, bnp + 96,
                                       skiph, x, wp1, wp2, bsum1, bsum2,
                                       lw, lb, out, N);
    } else {
        // ---- fallback: atomic scatter, fp32 ----
        size_t Npad = ((size_t)N + 255) & ~(size_t)255;
        float* fdinv = (float*)d_ws;
        float* fA = fdinv + Npad;
        float* fB = fA + (size_t)N * HF;
        float* fC = fB + (size_t)N * HF;
        int bEF = (int)(((long long)E * HF + T - 1) / T);
        int bH = (N + 255) / 256;

        k_initdeg<<<bN, T, 0, stream>>>(fdinv, N);
        k_deg_only<<<bE, T, 0, stream>>>(dst, ew, fdinv, E);
        k_dinv_f<<<bN, T, 0, stream>>>(fdinv, N);

        k_xw1_f<<<bNF, T, 0, stream>>>(x, g1w, fA, N);
        k_selfloop<<<bNF, T, 0, stream>>>(fA, fdinv, fB, N);
        k_scatter<<<bEF, T, 0, stream>>>(src, dst, ew, fdinv, fA, fB, E * HF);
        k_post<<<bNF, T, 0, stream>>>(fB, g1b, bn1g, bn1b, bn1m, bn1v, fC, N);

        k_xw2_f<<<bN8, T, 0, stream>>>(fC, g2w, fA, N);
        k_selfloop<<<bNF, T, 0, stream>>>(fA, fdinv, fB, N);
        k_scatter<<<bEF, T, 0, stream>>>(src, dst, ew, fdinv, fA, fB, E * HF);
        k_post<<<bNF, T, 0, stream>>>(fB, g2b, bn2g, bn2b, bn2m, bn2v, fB, N);

        k_head<<<bH, T, 0, stream>>>(fC, fB, x, w1ih, b1ih, b1hh, w2ih, b2ih, b2hh,
                                     lw, lb, out, N);
    }
}

// Round 14
// 265.937 us; speedup vs baseline: 1.1983x; 1.0216x over previous
//
#include <hip/hip_runtime.h>
#include <hip/hip_fp16.h>
#include <math.h>

#define BN_EPS 1e-5f
#define HF 32          // hidden features
#define BS 256         // nodes per bucket (8-bit dloc)
#define KEDGE 4096     // edges per binsort block (512 thr x 8 edges)
#define MAXNB 800      // max buckets (NB=782 for N=200k)
#define SCAP 5504      // sortb LDS record-stage capacity (44KB)
#define WQ14 16383.0f  // 14-bit norm quantization
#define WQ22 4194303.0f // 22-bit raw-weight quantization (binsort staging)

typedef _Float16 half8 __attribute__((ext_vector_type(8)));
typedef float f32x4 __attribute__((ext_vector_type(4)));
typedef float f32x2 __attribute__((ext_vector_type(2)));

// fast transcendentals (trans pipe)
__device__ __forceinline__ float fsig(float x) {
    return __builtin_amdgcn_rcpf(1.0f + __expf(-x));
}
__device__ __forceinline__ float ftanh(float x) {
    return 1.0f - 2.0f * __builtin_amdgcn_rcpf(1.0f + __expf(2.0f * x));
}

// ---------- fp8 e4m3 (OCP) helpers: HW converters with SW fallback ----------

__device__ __forceinline__ float e4m3_to_f32_sw(unsigned v) {
    unsigned s = v & 0x80u, E = (v >> 3) & 0xFu, m = v & 7u;
    float r = E ? ldexpf((float)(8 + m), (int)E - 10) : ldexpf((float)m, -9);
    return s ? -r : r;
}

__device__ __forceinline__ unsigned f32_to_e4m3_sw(float x) {
    float ax = fabsf(x);
    unsigned s = x < 0.0f ? 0x80u : 0u;
    if (!(ax > 0.0f)) return s;
    if (ax >= 448.0f) return s | 0x7Eu;
    int e;
    float m = frexpf(ax, &e);      // ax = m * 2^e, m in [0.5,1)
    int E = e - 1 + 7;
    if (E >= 1) {
        int q = (int)(m * 16.0f + 0.5f);
        if (q == 16) { q = 8; E += 1; if (E > 15) return s | 0x7Eu; }
        return s | (unsigned)(E << 3) | (unsigned)(q - 8);
    }
    int q = (int)(ax * 512.0f + 0.5f);
    if (q > 7) return s | 0x08u;
    return s | (unsigned)q;
}

__device__ __forceinline__ void dec8(uint2 r, float* f) {
#if __has_builtin(__builtin_amdgcn_cvt_pk_f32_fp8)
    f32x2 p0 = __builtin_amdgcn_cvt_pk_f32_fp8((int)r.x, false);
    f32x2 p1 = __builtin_amdgcn_cvt_pk_f32_fp8((int)r.x, true);
    f32x2 p2 = __builtin_amdgcn_cvt_pk_f32_fp8((int)r.y, false);
    f32x2 p3 = __builtin_amdgcn_cvt_pk_f32_fp8((int)r.y, true);
    f[0] = p0[0]; f[1] = p0[1]; f[2] = p1[0]; f[3] = p1[1];
    f[4] = p2[0]; f[5] = p2[1]; f[6] = p3[0]; f[7] = p3[1];
#else
#pragma unroll
    for (int k = 0; k < 4; ++k) f[k] = e4m3_to_f32_sw((r.x >> (8 * k)) & 0xFFu);
#pragma unroll
    for (int k = 0; k < 4; ++k) f[4 + k] = e4m3_to_f32_sw((r.y >> (8 * k)) & 0xFFu);
#endif
}

__device__ __forceinline__ uint2 enc8(const float* o) {
#if __has_builtin(__builtin_amdgcn_cvt_pk_fp8_f32)
    int w0 = 0, w1 = 0;
    w0 = __builtin_amdgcn_cvt_pk_fp8_f32(o[0], o[1], w0, false);
    w0 = __builtin_amdgcn_cvt_pk_fp8_f32(o[2], o[3], w0, true);
    w1 = __builtin_amdgcn_cvt_pk_fp8_f32(o[4], o[5], w1, false);
    w1 = __builtin_amdgcn_cvt_pk_fp8_f32(o[6], o[7], w1, true);
    return make_uint2((unsigned)w0, (unsigned)w1);
#else
    unsigned a = 0, b = 0;
#pragma unroll
    for (int k = 0; k < 4; ++k) a |= f32_to_e4m3_sw(o[k]) << (8 * k);
#pragma unroll
    for (int k = 0; k < 4; ++k) b |= f32_to_e4m3_sw(o[4 + k]) << (8 * k);
    return make_uint2(a, b);
#endif
}

// ====== gather over an 8-padded record segment (pads are ZEROED records) ======
// r13: scalar tail killed via 4-pad; r14: pad to 8 -- single uniform 8-batch loop,
// no tail branch at all. Pads decode to nm=0 / row 0 (harmless broadcast). Zero
// extra registers (r11 lesson: VGPRs cost TLP in this latency-bound regime).
__device__ __forceinline__ void gather_seg8(
        const unsigned* __restrict__ r, int cnp,
        const unsigned char* __restrict__ rows, int lane, float* acc) {
    const float qs = 1.0f / WQ14;
    uint4 na, nb;
    if (8 <= cnp) { na = *(const uint4*)(r); nb = *(const uint4*)(r + 4); }
    int e = 0;
    for (; e + 8 <= cnp; e += 8) {
        uint4 ua = na, ub = nb;
        if (e + 16 <= cnp) { na = *(const uint4*)(r + e + 8); nb = *(const uint4*)(r + e + 12); }
        unsigned u[8] = {ua.x, ua.y, ua.z, ua.w, ub.x, ub.y, ub.z, ub.w};
        uint2 rw[8];
#pragma unroll
        for (int q = 0; q < 8; ++q)
            rw[q] = ((const uint2*)(rows + ((size_t)(u[q] >> 14) << 5)))[lane];
        float nm[8];
#pragma unroll
        for (int q = 0; q < 8; ++q)
            nm[q] = (float)(u[q] & 16383u) * qs;
#pragma unroll
        for (int q = 0; q < 8; ++q) {
            float f[8];
            dec8(rw[q], f);
#pragma unroll
            for (int k = 0; k < 8; ++k) acc[k] += nm[q] * f[k];
        }
    }
}

// ================= Phase A: register-staged direct scatter into buckets =================
// r7 lesson: per-block cost scales with NB, so fewer/fatter blocks win (512 thr x 4096).
// Vector loads; record handling compile-time-indexed (r6's runtime loop spilled).

__global__ __launch_bounds__(512) void k_binsort(
        const int* __restrict__ src, const int* __restrict__ dst,
        const float* __restrict__ ew, int E, int NB, int bcap,
        int* __restrict__ gcur, uint2* __restrict__ recs) {
    __shared__ int hist[MAXNB], curs[MAXNB];

    int tid = threadIdx.x;
    int base = blockIdx.x * KEDGE;
    int cnt = min(KEDGE, E - base);

    for (int i = tid; i < NB; i += 512) hist[i] = 0;
    __syncthreads();

    uint2 rec[8];
    int eb = base + tid * 8;
    int rem = cnt - tid * 8;           // edges owned by this thread (<=0 .. 8)
    if (rem >= 8) {                    // fast path: whole-block for non-tail blocks
        int4 s0 = *(const int4*)(src + eb);
        int4 s1 = *(const int4*)(src + eb + 4);
        int4 d0 = *(const int4*)(dst + eb);
        int4 d1 = *(const int4*)(dst + eb + 4);
        float4 w0 = *(const float4*)(ew + eb);
        float4 w1 = *(const float4*)(ew + eb + 4);
        int ss[8] = {s0.x, s0.y, s0.z, s0.w, s1.x, s1.y, s1.z, s1.w};
        int dd[8] = {d0.x, d0.y, d0.z, d0.w, d1.x, d1.y, d1.z, d1.w};
        float ww[8] = {w0.x, w0.y, w0.z, w0.w, w1.x, w1.y, w1.z, w1.w};
#pragma unroll
        for (int k = 0; k < 8; ++k) {
            unsigned q = (unsigned)(ww[k] * WQ22 + 0.5f);
            if (q > 4194303u) q = 4194303u;
            int b = dd[k] >> 8;
            rec[k] = make_uint2(((unsigned)ss[k] << 8) | (unsigned)(dd[k] & 255),
                                ((unsigned)b << 22) | q);
        }
    } else {
#pragma unroll
        for (int k = 0; k < 8; ++k) {
            if (k < rem) {
                int s = src[eb + k];
                int d = dst[eb + k];
                float w = ew[eb + k];
                unsigned q = (unsigned)(w * WQ22 + 0.5f);
                if (q > 4194303u) q = 4194303u;
                int b = d >> 8;
                rec[k] = make_uint2(((unsigned)s << 8) | (unsigned)(d & 255),
                                    ((unsigned)b << 22) | q);
            }
        }
    }
#pragma unroll
    for (int k = 0; k < 8; ++k)
        if (k < rem) atomicAdd(&hist[rec[k].y >> 22], 1);
    __syncthreads();

    // bucket base in global recs region; curs counts up from it
    for (int b = tid; b < NB; b += 512) {
        int len = hist[b];
        curs[b] = len ? atomicAdd(&gcur[b], len) : 0;
    }
    __syncthreads();

#pragma unroll
    for (int k = 0; k < 8; ++k) {
        if (k < rem) {
            uint2 u = rec[k];
            int b = u.y >> 22;
            int off = atomicAdd(&curs[b], 1);
            if (off < bcap) recs[(size_t)b * bcap + off] = u;
        }
    }
}

// ====== Phase B: 4B records (8-padded segs, ZEROED pads) + CSR + dinv + y1 ======
// 1024 threads; LDS record staging so the CSR scatter never re-reads 25.6MB of
// global. pcnt stores the PADDED count (multiple of 8). Block 0 also does the
// one-time weight pack + bias sums + BN fold (bnp: sc1|sh1|sc2|sh2 x32).

__global__ __launch_bounds__(1024) void k_sortb(
        const uint2* __restrict__ recs, const int* __restrict__ gcur,
        int bcap, int bcap4,
        const float* __restrict__ x, const float* __restrict__ W1,
        unsigned* __restrict__ recs4, int* __restrict__ pstart,
        int* __restrict__ pcnt, float* __restrict__ dinv,
        unsigned char* __restrict__ y18,
        const float* __restrict__ wih1, const float* __restrict__ bih1,
        const float* __restrict__ bhh1, const float* __restrict__ wih2,
        const float* __restrict__ bih2, const float* __restrict__ bhh2,
        const float* __restrict__ bn1g, const float* __restrict__ bn1b,
        const float* __restrict__ bn1m, const float* __restrict__ bn1v,
        const float* __restrict__ bn2g, const float* __restrict__ bn2b,
        const float* __restrict__ bn2m, const float* __restrict__ bn2v,
        __half* __restrict__ wp1, __half* __restrict__ wp2,
        float* __restrict__ bsum1, float* __restrict__ bsum2,
        float* __restrict__ bnp, int n) {
    __shared__ uint2 srec[SCAP];
    __shared__ int hist[BS], excl4[BS], curs[BS], wsm[BS];
    __shared__ float sdv[BS];
    __shared__ float sW1[128];

    int b = blockIdx.x, tid = threadIdx.x;
    int cnt = min(gcur[b], bcap);
    const uint2* r = recs + (size_t)b * bcap;
    const float dq = 1.0f / WQ22;

    // one-time prep work (block 0 only; independent of this block's bucket work)
    if (b == 0) {
        const int tg[6] = {0, 16, 64, 80, 96, 112};
        for (int idx = tid; idx < 9600; idx += 1024) {
            if (idx < 6144) {
                int t = idx >> 10, rm = idx & 1023;
                int kc = rm >> 9, rm2 = rm & 511;
                int lane = rm2 >> 3, j = rm2 & 7;
                int g = tg[t] + (lane & 15);
                int k = kc * 32 + (lane >> 4) * 8 + j;
                wp1[idx] = __float2half(wih1[g * 64 + k]);
            } else if (idx < 9216) {
                int i2 = idx - 6144;
                int t = i2 >> 9, rm2 = i2 & 511;
                int lane = rm2 >> 3, j = rm2 & 7;
                int g = tg[t] + (lane & 15);
                int k = (lane >> 4) * 8 + j;
                wp2[i2] = __float2half(wih2[g * 32 + k]);
            } else if (idx < 9344) {
                int i = idx - 9216;
                bsum1[i] = bih1[i] + bhh1[i];
            } else if (idx < 9472) {
                int i = idx - 9344;
                bsum2[i] = bih2[i] + bhh2[i];
            } else {
                int f2 = idx - 9472;        // 0..127
                int f = f2 & 31;
                if (f2 < 32) {
                    bnp[f2] = bn1g[f] * rsqrtf(bn1v[f] + BN_EPS);
                } else if (f2 < 64) {
                    float sc = bn1g[f] * rsqrtf(bn1v[f] + BN_EPS);
                    bnp[f2] = bn1b[f] - bn1m[f] * sc;
                } else if (f2 < 96) {
                    bnp[f2] = bn2g[f] * rsqrtf(bn2v[f] + BN_EPS);
                } else {
                    float sc = bn2g[f] * rsqrtf(bn2v[f] + BN_EPS);
                    bnp[f2] = bn2b[f] - bn2m[f] * sc;
                }
            }
        }
    }

    if (tid < BS) { hist[tid] = 0; wsm[tid] = 0; }
    if (tid >= 256 && tid < 384) sW1[tid - 256] = W1[tid - 256];
    __syncthreads();

    for (int i = tid; i < cnt; i += 1024) {
        uint2 u = r[i];
        if (i < SCAP) srec[i] = u;
        int dl = u.x & 255;
        atomicAdd(&hist[dl], 1);
        atomicAdd(&wsm[dl], (int)(u.y & 4194303u));
    }
    __syncthreads();

    if (tid < BS) {
        int g = b * BS + tid;
        sdv[tid] = (g < n) ? rsqrtf(1.0f + (float)wsm[tid] * dq) : 0.0f;
    }
    // exclusive scan over 8-padded lengths -> 8-aligned per-node segments
    if (tid < 64) {
        int run = 0;
        for (int c = 0; c < BS; c += 64) {
            int idx = c + tid;
            int v = (hist[idx] + 7) & ~7;
            int incl = v;
#pragma unroll
            for (int o = 1; o < 64; o <<= 1) {
                int up = __shfl_up(incl, o, 64);
                if (tid >= o) incl += up;
            }
            int e = run + incl - v;
            excl4[idx] = e; curs[idx] = e;
            run += __shfl(incl, 63, 64);
        }
    }
    __syncthreads();

    unsigned* out4 = recs4 + (size_t)b * bcap4;
    for (int i = tid; i < cnt; i += 1024) {
        uint2 u = (i < SCAP) ? srec[i] : r[i];
        int dl = u.x & 255;
        int pos = atomicAdd(&curs[dl], 1);
        float qn = (float)(u.y & 4194303u) * dq * sdv[dl];  // w * dinv_d
        unsigned q = (unsigned)(qn * WQ14 + 0.5f);
        if (q > 16383u) q = 16383u;
        out4[pos] = ((u.x >> 8) << 14) | q;
    }

    // y18[g] = Q(dinv_g * (x_g @ W1)): 4 threads/node, 8 features each
    {
        int node = tid >> 2, q = tid & 3;
        int g = b * BS + node;
        if (g < n) {
            float4 xv = *(const float4*)(x + (size_t)g * 4);
            float sc = sdv[node];
            int f0 = q * 8;
            float o[8];
#pragma unroll
            for (int k = 0; k < 8; ++k)
                o[k] = sc * (xv.x * sW1[f0 + k] + xv.y * sW1[32 + f0 + k] +
                             xv.z * sW1[64 + f0 + k] + xv.w * sW1[96 + f0 + k]);
            ((uint2*)(y18 + ((size_t)g << 5)))[q] = enc8(o);
        }
    }

    if (tid < BS) {
        int g = b * BS + tid;
        // ZERO the <=7 pad slots (disjoint from scattered slots -- no race):
        // zero record -> nm=0, row 0 -> contributes nothing in gathers.
        int cnp = (hist[tid] + 7) & ~7;
        int end = excl4[tid] + hist[tid];
        int pend = excl4[tid] + cnp;
        for (int p2 = end; p2 < pend; ++p2) out4[p2] = 0u;
        if (g < n) {
            pstart[g] = b * bcap4 + excl4[tid];
            pcnt[g] = cnp;            // PADDED count
            dinv[g] = sdv[tid];
        }
    }
}

// ====== layer 1: fp8-row gather over prescaled y1 + BN + fused xw2 -> A8, skiph(h1) ======
// r10 operating point (depth-1 prefetch, ~60 VGPR) + r14 uniform 8-padded loop.

__global__ __launch_bounds__(256) void k_g1w2(
        const unsigned* __restrict__ recs4, const int* __restrict__ pstart,
        const int* __restrict__ pcnt, const float* __restrict__ dinv,
        const unsigned char* __restrict__ y18, const float* __restrict__ W2,
        const float* __restrict__ bias, const float* __restrict__ bnsc,
        const float* __restrict__ bnsh,
        __half* __restrict__ skiph, unsigned char* __restrict__ A8, int n) {
    __shared__ float sW2[1024];
    __shared__ float sh1[64][33];
    int tid = threadIdx.x;

    int nl = tid >> 2;
    int g = blockIdx.x * 64 + nl;
    int lane = tid & 3;
    int fq = lane * 8;
    bool act = g < n;

    // hoisted per-node scalars + self row (latency overlap with sW2 staging)
    float dig = 0.0f;
    int cn = 0;
    const unsigned* r = recs4;
    uint2 sr = make_uint2(0u, 0u);
    if (act) {
        dig = dinv[g];
        cn = pcnt[g];                 // already 8-padded
        r = recs4 + pstart[g];
        sr = ((const uint2*)(y18 + ((size_t)g << 5)))[lane];
    }

    // stage W2 (read only in phase 2 -- no barrier needed here)
    for (int i = tid; i < 1024; i += 256) sW2[i] = W2[i];

    float acc[8];
#pragma unroll
    for (int k = 0; k < 8; ++k) acc[k] = 0.0f;

    if (act) {
        {
            // self-loop: dinv_g * y18hat[g] = dinv_g^2 * y1[g]
            float f[8];
            dec8(sr, f);
#pragma unroll
            for (int k = 0; k < 8; ++k) acc[k] = dig * f[k];
        }
        gather_seg8(r, cn, y18, lane, acc);
    }

    // h1 epilogue: bias + relu + folded BN; stage for xw2; emit fp16 h1 slice
    float o[8];
#pragma unroll
    for (int k = 0; k < 8; ++k) {
        float v = fmaxf(acc[k] + bias[fq + k], 0.0f);
        o[k] = v * bnsc[fq + k] + bnsh[fq + k];
        sh1[nl][fq + k] = o[k];
    }
    if (act) {
        union { __half h[8]; uint4 q; } hv;
#pragma unroll
        for (int k = 0; k < 8; ++k) hv.h[k] = __float2half(o[k]);
        *(uint4*)(skiph + (size_t)g * 32 + fq) = hv.q;
    }
    __syncthreads();

    // phase 2: A8[g] = Q(dinv_g * (h1[g] @ W2)) -> layer-2 rows carry dinv_src
    if (act) {
        float a2[8];
#pragma unroll
        for (int j = 0; j < 8; ++j) a2[j] = 0.0f;
#pragma unroll 4
        for (int k = 0; k < 32; ++k) {
            float h = sh1[nl][k];
            const float* wr = sW2 + k * 32 + fq;
#pragma unroll
            for (int j = 0; j < 8; ++j) a2[j] += h * wr[j];
        }
#pragma unroll
        for (int j = 0; j < 8; ++j) a2[j] *= dig;
        ((uint2*)(A8 + ((size_t)g << 5)))[lane] = enc8(a2);
    }
}

// ===== layer 2 gather + MFMA head fused: h2 never round-trips through HBM =====
// h1 row (head-phase input) prefetched at entry -- latency hides under the gather.

__global__ __launch_bounds__(256) void k_g2head(
        const unsigned* __restrict__ recs4, const int* __restrict__ pstart,
        const int* __restrict__ pcnt, const float* __restrict__ dinv,
        const unsigned char* __restrict__ A8,
        const float* __restrict__ bias, const float* __restrict__ bnsc,
        const float* __restrict__ bnsh,
        const __half* __restrict__ skiph, const float* __restrict__ x,
        const __half* __restrict__ wp1, const __half* __restrict__ wp2,
        const float* __restrict__ bsum1, const float* __restrict__ bsum2,
        const float* __restrict__ lw, const float* __restrict__ lb,
        float* __restrict__ out, int n) {
    __shared__ __align__(16) __half h2s[64][40];
    __shared__ __align__(16) __half H1lds[4 * 16 * 40];
    int tid = threadIdx.x;
    int nl = tid >> 2;
    int g = blockIdx.x * 64 + nl;
    int lane = tid & 3;
    int fq = lane * 8;
    bool act = g < n;

    // head-phase coordinates + early h1 prefetch (used only after the gather)
    int w = tid >> 6, l = tid & 63;
    int quad = l >> 4, c = l & 15;
    int node_base = blockIdx.x * 64 + w * 16;
    int arow = node_base + c; if (arow > n - 1) arow = n - 1;
    int lr = arow - blockIdx.x * 64;
    half8 a0 = *(const half8*)(skiph + (size_t)arow * 32 + quad * 8);  // h1

    // hoisted per-node scalars + self row
    float dig = 0.0f;
    int cn = 0;
    const unsigned* r = recs4;
    uint2 sr = make_uint2(0u, 0u);
    if (act) {
        dig = dinv[g];
        cn = pcnt[g];                 // already 8-padded
        r = recs4 + pstart[g];
        sr = ((const uint2*)(A8 + ((size_t)g << 5)))[lane];
    }

    // ---------------- gather phase (h2 = GCN2 output) ----------------
    float acc[8];
#pragma unroll
    for (int k = 0; k < 8; ++k) acc[k] = 0.0f;

    if (act) {
        {
            // self-loop: dinv_g * A8hat[g] = dinv_g^2 * A[g]
            float f[8];
            dec8(sr, f);
#pragma unroll
            for (int k = 0; k < 8; ++k) acc[k] = dig * f[k];
        }
        gather_seg8(r, cn, A8, lane, acc);

        // epilogue: bias + relu + folded BN -> h2 into LDS
        union { __half h[8]; uint4 q; } hv;
#pragma unroll
        for (int k = 0; k < 8; ++k) {
            float v = fmaxf(acc[k] + bias[fq + k], 0.0f);
            hv.h[k] = __float2half(v * bnsc[fq + k] + bnsh[fq + k]);
        }
        *(uint4*)(&h2s[nl][fq]) = hv.q;
    }
    __syncthreads();

    // ---------------- head phase (LSTM1 + LSTM2 + linear) ----------------
    half8 a1 = *(const half8*)(&h2s[lr][quad * 8]);                    // h2 (LDS)

    const half8* b1 = (const half8*)wp1;
    f32x4 d[6];
#pragma unroll
    for (int t = 0; t < 6; ++t) {
        f32x4 ac = {0.0f, 0.0f, 0.0f, 0.0f};
        ac = __builtin_amdgcn_mfma_f32_16x16x32_f16(a0, b1[(t * 2 + 0) * 64 + l], ac, 0, 0, 0);
        ac = __builtin_amdgcn_mfma_f32_16x16x32_f16(a1, b1[(t * 2 + 1) * 64 + l], ac, 0, 0, 0);
        d[t] = ac;
    }

    float bi0 = bsum1[c],      bi1 = bsum1[16 + c];
    float bg0 = bsum1[64 + c], bg1 = bsum1[80 + c];
    float bo0 = bsum1[96 + c], bo1 = bsum1[112 + c];
    float lwc0 = lw[c], lwc1 = lw[c + 16];

    float pa[4];
#pragma unroll
    for (int r2 = 0; r2 < 4; ++r2) {
        float cc0 = fsig(d[0][r2] + bi0) * ftanh(d[2][r2] + bg0);
        float h0 = fsig(d[4][r2] + bo0) * ftanh(cc0);
        float cc1 = fsig(d[1][r2] + bi1) * ftanh(d[3][r2] + bg1);
        float h1 = fsig(d[5][r2] + bo1) * ftanh(cc1);
        pa[r2] = fmaxf(h0, 0.0f) * lwc0 + fmaxf(h1, 0.0f) * lwc1;
        __half* hp = H1lds + (w * 16 + quad * 4 + r2) * 40;
        hp[c] = __float2half(h0);
        hp[c + 16] = __float2half(h1);
    }
    __syncthreads();

    half8 a2 = *(const half8*)(H1lds + (w * 16 + c) * 40 + quad * 8);

    const half8* b2 = (const half8*)wp2;
    f32x4 e2[6];
#pragma unroll
    for (int t = 0; t < 6; ++t) {
        f32x4 ac = {0.0f, 0.0f, 0.0f, 0.0f};
        e2[t] = __builtin_amdgcn_mfma_f32_16x16x32_f16(a2, b2[t * 64 + l], ac, 0, 0, 0);
    }

    float ci0 = bsum2[c],      ci1 = bsum2[16 + c];
    float cg0 = bsum2[64 + c], cg1 = bsum2[80 + c];
    float co0 = bsum2[96 + c], co1 = bsum2[112 + c];
    float lw2c0 = lw[32 + c], lw2c1 = lw[48 + c];
#pragma unroll
    for (int r2 = 0; r2 < 4; ++r2) {
        float cc0 = fsig(e2[0][r2] + ci0) * ftanh(e2[2][r2] + cg0);
        float h0 = fsig(e2[4][r2] + co0) * ftanh(cc0);
        float cc1 = fsig(e2[1][r2] + ci1) * ftanh(e2[3][r2] + cg1);
        float h1 = fsig(e2[5][r2] + co1) * ftanh(cc1);
        pa[r2] += fmaxf(h0, 0.0f) * lw2c0 + fmaxf(h1, 0.0f) * lw2c1;
    }

#pragma unroll
    for (int m = 1; m < 16; m <<= 1) {
#pragma unroll
        for (int r2 = 0; r2 < 4; ++r2) pa[r2] += __shfl_xor(pa[r2], m, 64);
    }

    if (c < 4) {
        int node = node_base + quad * 4 + c;
        if (node < n) {
            const float4 xv = *(const float4*)(x + (size_t)node * 4);
            out[node] = pa[c] + lb[0]
                + fmaxf(xv.x, 0.0f) * lw[64] + fmaxf(xv.y, 0.0f) * lw[65]
                + fmaxf(xv.z, 0.0f) * lw[66] + fmaxf(xv.w, 0.0f) * lw[67];
        }
    }
}

// ================= fallback (atomic scatter, fp32) =================

__global__ void k_initdeg(float* __restrict__ deg, int n) {
    int i = blockIdx.x * blockDim.x + threadIdx.x;
    if (i < n) deg[i] = 1.0f;
}

__global__ void k_deg_only(const int* __restrict__ dst, const float* __restrict__ ew,
                           float* __restrict__ deg, int E) {
    int e = blockIdx.x * blockDim.x + threadIdx.x;
    if (e < E) atomicAdd(&deg[dst[e]], ew[e]);
}

__global__ void k_dinv_f(float* __restrict__ deg, int n) {
    int i = blockIdx.x * blockDim.x + threadIdx.x;
    if (i < n) {
        float d = deg[i];
        deg[i] = d > 0.0f ? rsqrtf(d) : 0.0f;
    }
}

__global__ void k_xw1_f(const float* __restrict__ x, const float* __restrict__ W,
                        float* __restrict__ out, int n) {
    int idx = blockIdx.x * blockDim.x + threadIdx.x;
    if (idx >= n * HF) return;
    int nn = idx >> 5, f = idx & 31;
    const float4 xr = *(const float4*)(x + (size_t)nn * 4);
    out[idx] = xr.x * W[f] + xr.y * W[32 + f] + xr.z * W[64 + f] + xr.w * W[96 + f];
}

__global__ void k_xw2_f(const float* __restrict__ Hin, const float* __restrict__ W,
                        float* __restrict__ out, int n) {
    __shared__ float sW[32 * 32];
    __shared__ float sH[8][32];
    int tid = threadIdx.x;
    for (int i = tid; i < 1024; i += 256) sW[i] = W[i];
    int r = tid >> 5, f = tid & 31;
    int nn = blockIdx.x * 8 + r;
    if (nn < n) sH[r][f] = Hin[(size_t)nn * HF + f];
    __syncthreads();
    if (nn >= n) return;
    float acc = 0.0f;
#pragma unroll
    for (int k = 0; k < 32; ++k) acc += sH[r][k] * sW[k * 32 + f];
    out[(size_t)nn * HF + f] = acc;
}

__global__ void k_selfloop(const float* __restrict__ A, const float* __restrict__ dinv,
                           float* __restrict__ B, int n) {
    int idx = blockIdx.x * blockDim.x + threadIdx.x;
    if (idx >= n * HF) return;
    int nn = idx >> 5;
    float di = dinv[nn];
    B[idx] = di * di * A[idx];
}

__global__ void k_scatter(const int* __restrict__ src, const int* __restrict__ dst,
                          const float* __restrict__ ew, const float* __restrict__ dinv,
                          const float* __restrict__ A, float* __restrict__ B, int total) {
    int idx = blockIdx.x * blockDim.x + threadIdx.x;
    if (idx >= total) return;
    int e = idx >> 5, f = idx & 31;
    int s = src[e], d = dst[e];
    float norm = dinv[s] * ew[e] * dinv[d];
    atomicAdd(&B[d * HF + f], norm * A[s * HF + f]);
}

__global__ void k_post(const float* __restrict__ B, const float* __restrict__ bias,
                       const float* __restrict__ gamma, const float* __restrict__ beta,
                       const float* __restrict__ mean, const float* __restrict__ var,
                       float* __restrict__ Hout, int n) {
    int idx = blockIdx.x * blockDim.x + threadIdx.x;
    if (idx >= n * HF) return;
    int f = idx & 31;
    float v = fmaxf(B[idx] + bias[f], 0.0f);
    float sc = gamma[f] * rsqrtf(var[f] + BN_EPS);
    Hout[idx] = (v - mean[f]) * sc + beta[f];
}

__global__ __launch_bounds__(256) void k_head(
        const float* __restrict__ h1, const float* __restrict__ h2,
        const float* __restrict__ x,
        const float* __restrict__ wih1, const float* __restrict__ bih1, const float* __restrict__ bhh1,
        const float* __restrict__ wih2, const float* __restrict__ bih2, const float* __restrict__ bhh2,
        const float* __restrict__ lw, const float* __restrict__ lb,
        float* __restrict__ out, int n) {
    __shared__ float sH1[32 * 256];
    int tid = threadIdx.x;
    int nn = blockIdx.x * 256 + tid;
    if (nn >= n) return;

    const float4* a = (const float4*)(h1 + (size_t)nn * HF);
    const float4* b = (const float4*)(h2 + (size_t)nn * HF);
    float skip[64];
#pragma unroll
    for (int q = 0; q < 8; ++q) {
        float4 v = a[q];
        skip[4 * q] = v.x; skip[4 * q + 1] = v.y; skip[4 * q + 2] = v.z; skip[4 * q + 3] = v.w;
        float4 u = b[q];
        skip[32 + 4 * q] = u.x; skip[33 + 4 * q] = u.y; skip[34 + 4 * q] = u.z; skip[35 + 4 * q] = u.w;
    }

    float oa = lb[0];
#pragma unroll 1
    for (int j = 0; j < 32; ++j) {
        const float4* wi = (const float4*)(wih1 + (size_t)j * 64);
        const float4* wg = (const float4*)(wih1 + (size_t)(64 + j) * 64);
        const float4* wo = (const float4*)(wih1 + (size_t)(96 + j) * 64);
        float gi = bih1[j] + bhh1[j];
        float gg = bih1[64 + j] + bhh1[64 + j];
        float go = bih1[96 + j] + bhh1[96 + j];
#pragma unroll
        for (int q = 0; q < 16; ++q) {
            float4 aa = wi[q], bb = wg[q], cc4 = wo[q];
            float s0 = skip[4 * q], s1 = skip[4 * q + 1], s2 = skip[4 * q + 2], s3 = skip[4 * q + 3];
            gi += aa.x * s0 + aa.y * s1 + aa.z * s2 + aa.w * s3;
            gg += bb.x * s0 + bb.y * s1 + bb.z * s2 + bb.w * s3;
            go += cc4.x * s0 + cc4.y * s1 + cc4.z * s2 + cc4.w * s3;
        }
        float cc = fsig(gi) * ftanh(gg);
        float hh = fsig(go) * ftanh(cc);
        sH1[j * 256 + tid] = hh;
        oa += fmaxf(hh, 0.0f) * lw[j];
    }

#pragma unroll 1
    for (int j = 0; j < 32; ++j) {
        const float4* wi = (const float4*)(wih2 + (size_t)j * 32);
        const float4* wg = (const float4*)(wih2 + (size_t)(64 + j) * 32);
        const float4* wo = (const float4*)(wih2 + (size_t)(96 + j) * 32);
        float gi = bih2[j] + bhh2[j];
        float gg = bih2[64 + j] + bhh2[64 + j];
        float go = bih2[96 + j] + bhh2[96 + j];
#pragma unroll
        for (int q = 0; q < 8; ++q) {
            float4 aa = wi[q], bb = wg[q], cc4 = wo[q];
            float s0 = sH1[(4 * q) * 256 + tid], s1 = sH1[(4 * q + 1) * 256 + tid];
            float s2 = sH1[(4 * q + 2) * 256 + tid], s3 = sH1[(4 * q + 3) * 256 + tid];
            gi += aa.x * s0 + aa.y * s1 + aa.z * s2 + aa.w * s3;
            gg += bb.x * s0 + bb.y * s1 + bb.z * s2 + bb.w * s3;
            go += cc4.x * s0 + cc4.y * s1 + cc4.z * s2 + cc4.w * s3;
        }
        float cc = fsig(gi) * ftanh(gg);
        float hh = fsig(go) * ftanh(cc);
        oa += fmaxf(hh, 0.0f) * lw[32 + j];
    }

    const float4 xv = *(const float4*)(x + (size_t)nn * 4);
    oa += fmaxf(xv.x, 0.0f) * lw[64] + fmaxf(xv.y, 0.0f) * lw[65] +
          fmaxf(xv.z, 0.0f) * lw[66] + fmaxf(xv.w, 0.0f) * lw[67];
    out[nn] = oa;
}

// ================= launch =================

extern "C" void kernel_launch(void* const* d_in, const int* in_sizes, int n_in,
                              void* d_out, int out_size, void* d_ws, size_t ws_size,
                              hipStream_t stream) {
    const float* x   = (const float*)d_in[0];
    const int*   ei  = (const int*)d_in[1];
    const float* ew  = (const float*)d_in[2];
    const float* g1w = (const float*)d_in[3];
    const float* g1b = (const float*)d_in[4];
    const float* g2w = (const float*)d_in[5];
    const float* g2b = (const float*)d_in[6];
    const float* bn1g = (const float*)d_in[7];
    const float* bn1b = (const float*)d_in[8];
    const float* bn1m = (const float*)d_in[9];
    const float* bn1v = (const float*)d_in[10];
    const float* bn2g = (const float*)d_in[11];
    const float* bn2b = (const float*)d_in[12];
    const float* bn2m = (const float*)d_in[13];
    const float* bn2v = (const float*)d_in[14];
    const float* w1ih = (const float*)d_in[15];
    const float* b1ih = (const float*)d_in[17];
    const float* b1hh = (const float*)d_in[18];
    const float* w2ih = (const float*)d_in[19];
    const float* b2ih = (const float*)d_in[21];
    const float* b2hh = (const float*)d_in[22];
    const float* lw   = (const float*)d_in[23];
    const float* lb   = (const float*)d_in[24];
    float* out = (float*)d_out;

    const int N = in_sizes[0] / 4;
    const int E = in_sizes[2];
    const int* src = ei;
    const int* dst = ei + E;

    const int T = 256;
    const int NB = (N + BS - 1) / BS;
    long long meanb = ((long long)BS * E) / (N > 0 ? N : 1);
    int bcap = (int)(meanb + meanb / 4 + 128);
    bcap = (bcap + 7) & ~7;
    int bcap4 = bcap + 7 * BS;  // room for per-node 8-alignment padding

    // workspace layout (256B-aligned regions)
    char* p = (char*)d_ws;
    auto alloc = [&](size_t bytes) { char* q = p; p += (bytes + 255) & ~(size_t)255; return q; };
    int*      gcur   = (int*)alloc(sizeof(int) * NB);
    uint2*    recs   = (uint2*)alloc(sizeof(uint2) * (size_t)NB * bcap);
    unsigned* recs4  = (unsigned*)alloc(sizeof(unsigned) * (size_t)NB * bcap4);
    float*    dinv   = (float*)alloc(sizeof(float) * N);
    int*      pstart = (int*)alloc(sizeof(int) * N);
    int*      pcnt   = (int*)alloc(sizeof(int) * N);
    unsigned char* y18 = (unsigned char*)alloc((size_t)N * HF);         // fp8 dinv*(x@W1)
    unsigned char* A8  = (unsigned char*)alloc((size_t)N * HF);         // fp8 dinv*(h1@W2)
    __half*   skiph  = (__half*)alloc(sizeof(__half) * (size_t)N * 32); // h1 f16 only
    __half*   wp1    = (__half*)alloc(sizeof(__half) * 6144);
    __half*   wp2    = (__half*)alloc(sizeof(__half) * 3072);
    float*    bsum1  = (float*)alloc(sizeof(float) * 128);
    float*    bsum2  = (float*)alloc(sizeof(float) * 128);
    float*    bnp    = (float*)alloc(sizeof(float) * 128);  // folded BN sc/sh
    size_t need = (size_t)(p - (char*)d_ws);

    int bN  = (N + T - 1) / T;
    int bE  = (E + T - 1) / T;
    int bNF = (N * HF + T - 1) / T;
    int bN8 = (N + 7) / 8;
    int bG  = (N + 63) / 64;
    int bBin = (E + KEDGE - 1) / KEDGE;

    if (ws_size >= need && NB <= MAXNB && N <= (1 << 18) && bcap <= SCAP) {
        // ---- build: memset cursor + bucket scatter + CSR/prep ----
        hipMemsetAsync(gcur, 0, sizeof(int) * NB, stream);
        k_binsort<<<bBin, 512, 0, stream>>>(src, dst, ew, E, NB, bcap, gcur, recs);
        k_sortb<<<NB, 1024, 0, stream>>>(recs, gcur, bcap, bcap4, x, g1w,
                                         recs4, pstart, pcnt, dinv, y18,
                                         w1ih, b1ih, b1hh, w2ih, b2ih, b2hh,
                                         bn1g, bn1b, bn1m, bn1v,
                                         bn2g, bn2b, bn2m, bn2v,
                                         wp1, wp2, bsum1, bsum2, bnp, N);

        // ---- layer 1: fp8 gather over prescaled y1 + fused xw2 -> skiph(h1), A8 ----
        k_g1w2<<<bG, T, 0, stream>>>(recs4, pstart, pcnt, dinv, y18, g2w,
                                     g1b, bnp, bnp + 32, skiph, A8, N);
        // ---- layer 2 gather + MFMA head fused ----
        k_g2head<<<bG, T, 0, stream>>>(recs4, pstart, pcnt, dinv, A8,
                                       g2b, bnp + 64, bnp + 96,
                                       skiph, x, wp1, wp2, bsum1, bsum2,
                                       lw, lb, out, N);
    } else {
        // ---- fallback: atomic scatter, fp32 ----
        size_t Npad = ((size_t)N + 255) & ~(size_t)255;
        float* fdinv = (float*)d_ws;
        float* fA = fdinv + Npad;
        float* fB = fA + (size_t)N * HF;
        float* fC = fB + (size_t)N * HF;
        int bEF = (int)(((long long)E * HF + T - 1) / T);
        int bH = (N + 255) / 256;

        k_initdeg<<<bN, T, 0, stream>>>(fdinv, N);
        k_deg_only<<<bE, T, 0, stream>>>(dst, ew, fdinv, E);
        k_dinv_f<<<bN, T, 0, stream>>>(fdinv, N);

        k_xw1_f<<<bNF, T, 0, stream>>>(x, g1w, fA, N);
        k_selfloop<<<bNF, T, 0, stream>>>(fA, fdinv, fB, N);
        k_scatter<<<bEF, T, 0, stream>>>(src, dst, ew, fdinv, fA, fB, E * HF);
        k_post<<<bNF, T, 0, stream>>>(fB, g1b, bn1g, bn1b, bn1m, bn1v, fC, N);

        k_xw2_f<<<bN8, T, 0, stream>>>(fC, g2w, fA, N);
        k_selfloop<<<bNF, T, 0, stream>>>(fA, fdinv, fB, N);
        k_scatter<<<bEF, T, 0, stream>>>(src, dst, ew, fdinv, fA, fB, E * HF);
        k_post<<<bNF, T, 0, stream>>>(fB, g2b, bn2g, bn2b, bn2m, bn2v, fB, N);

        k_head<<<bH, T, 0, stream>>>(fC, fB, x, w1ih, b1ih, b1hh, w2ih, b2ih, b2hh,
                                     lw, lb, out, N);
    }
}